// Round 9
// baseline (61.838 us; speedup 1.0000x reference)
//
#include <hip/hip_runtime.h>
#include <math.h>

#define NB 2
#define LSEQ 2048
#define DM 512
#define MM 64
#define CHK 64
#define NCHUNK 32

typedef __attribute__((ext_vector_type(8))) short short8v;
typedef __attribute__((ext_vector_type(4))) float f32x4;

__device__ __forceinline__ float get_ld(const float* __restrict__ logit) {
    float lg = *logit;
    float dec = 1.0f / (1.0f + expf(-lg));
    dec = fmaxf(dec, 1e-6f);
    return logf(dec);
}
__device__ __forceinline__ float cpos(float ld, int t) {
    return fminf(fmaxf(ld * (float)t, -20.0f), 20.0f);
}
__device__ __forceinline__ float phi_fn(float v) {
    return v > 0.0f ? v + 1.0f : expf(v);
}
__device__ __forceinline__ unsigned short f2bf(float f) {
    unsigned int u = __float_as_uint(f);
    u += 0x7FFFu + ((u >> 16) & 1u);   // RNE
    return (unsigned short)(u >> 16);
}
__device__ __forceinline__ float bf2f(unsigned short h) {
    unsigned int u = ((unsigned int)h) << 16;
    return __uint_as_float(u);
}
// load 8 f32, convert to 8 bf16 packed in a uint4
__device__ __forceinline__ uint4 cvt8(const float* __restrict__ p) {
    float4 a = *(const float4*)p;
    float4 b = *(const float4*)(p + 4);
    union { unsigned short u[8]; uint4 v; } r;
    r.u[0] = f2bf(a.x); r.u[1] = f2bf(a.y); r.u[2] = f2bf(a.z); r.u[3] = f2bf(a.w);
    r.u[4] = f2bf(b.x); r.u[5] = f2bf(b.y); r.u[6] = f2bf(b.z); r.u[7] = f2bf(b.w);
    return r.v;
}

// ---- fused QKV projection (cvt-on-the-fly) + W_o cvt slice ----
// grid (64, 6): y=0 QK (cols = Wq|Wk), y=1..4 V col slices, y=5 W_o cvt
__global__ __launch_bounds__(256) void gemm_proj(
    const float* __restrict__ x, const float* __restrict__ W_q,
    const float* __restrict__ W_k, const float* __restrict__ W_v,
    const float* __restrict__ W_o,
    unsigned short* __restrict__ Qh, unsigned short* __restrict__ Kh,
    unsigned short* __restrict__ Vh, unsigned short* __restrict__ Wob)
{
    const int cb = blockIdx.y;
    const int tid = threadIdx.x;
    if (cb == 5) {  // W_o -> bf16 (64 blocks x 4 float4)
        const int stride = 64 * 256;
#pragma unroll
        for (int it = 0; it < 4; ++it) {
            int i = blockIdx.x * 256 + tid + it * stride;
            float4 v = ((const float4*)W_o)[i];
            ushort4 o;
            o.x = f2bf(v.x); o.y = f2bf(v.y); o.z = f2bf(v.z); o.w = f2bf(v.w);
            ((ushort4*)Wob)[i] = o;
        }
        return;
    }

    __shared__ unsigned short As[64][40];
    __shared__ unsigned short Bs[128][40];
    const int brow = blockIdx.x * 64;
    const int lane = tid & 63, wid = tid >> 6;
    const int wr = wid >> 1, wc = wid & 1;
    const int lr = lane & 15, lk = lane >> 4;

    f32x4 acc[2][4];
#pragma unroll
    for (int i = 0; i < 2; ++i)
#pragma unroll
        for (int j = 0; j < 4; ++j) acc[i][j] = (f32x4)(0.f);

    for (int k0 = 0; k0 < DM; k0 += 32) {
        {   // A tile: 64x32 f32 -> bf16
            const int r = tid >> 2, kg = tid & 3;
            *(uint4*)&As[r][kg * 8] = cvt8(&x[(size_t)(brow + r) * DM + k0 + kg * 8]);
        }
#pragma unroll
        for (int i = 0; i < 2; ++i) {   // B tile: 128x32
            int c = tid * 2 + i;
            int r = c >> 2, kg = c & 3;
            const float* wsrc;
            if (cb == 0)
                wsrc = (r < 64) ? &W_q[(size_t)r * DM + k0 + kg * 8]
                                : &W_k[(size_t)(r - 64) * DM + k0 + kg * 8];
            else
                wsrc = &W_v[(size_t)((cb - 1) * 128 + r) * DM + k0 + kg * 8];
            *(uint4*)&Bs[r][kg * 8] = cvt8(wsrc);
        }
        __syncthreads();
        short8v af[2], bf[4];
#pragma unroll
        for (int mt = 0; mt < 2; ++mt)
            af[mt] = *(const short8v*)&As[wr * 32 + mt * 16 + lr][lk * 8];
#pragma unroll
        for (int nt = 0; nt < 4; ++nt)
            bf[nt] = *(const short8v*)&Bs[wc * 64 + nt * 16 + lr][lk * 8];
#pragma unroll
        for (int mt = 0; mt < 2; ++mt)
#pragma unroll
            for (int nt = 0; nt < 4; ++nt)
                acc[mt][nt] = __builtin_amdgcn_mfma_f32_16x16x32_bf16(
                    af[mt], bf[nt], acc[mt][nt], 0, 0, 0);
        __syncthreads();
    }

#pragma unroll
    for (int mt = 0; mt < 2; ++mt)
#pragma unroll
        for (int nt = 0; nt < 4; ++nt) {
            const int col = wc * 64 + nt * 16 + lr;
#pragma unroll
            for (int j = 0; j < 4; ++j) {
                const int row = brow + wr * 32 + mt * 16 + lk * 4 + j;
                float v = acc[mt][nt][j];
                if (cb == 0) {
                    v = phi_fn(v);
                    if (col < 64)
                        Qh[(size_t)row * MM + col] = f2bf(v * 0.125f);
                    else
                        Kh[(size_t)row * MM + (col - 64)] = f2bf(v);
                } else {
                    Vh[(size_t)row * DM + (cb - 1) * 128 + col] = f2bf(v);
                }
            }
        }
}

// ---- intra-chunk attention + summaries, all MFMA; OI/KV emitted bf16 ----
__global__ __launch_bounds__(256) void chunk_local_mfma(
    const unsigned short* __restrict__ Qb, const unsigned short* __restrict__ Kb,
    const unsigned short* __restrict__ Vb, const float* __restrict__ logit,
    unsigned short* __restrict__ OI, float* __restrict__ DI,
    unsigned short* __restrict__ KV, float* __restrict__ KZ)
{
    const int chunk = blockIdx.x, dg = blockIdx.y, b = blockIdx.z;
    const int tid = threadIdx.x;
    const int lane = tid & 63, wid = tid >> 6;
    const int wr = wid >> 1, wc = wid & 1;
    const int lr = lane & 15, lk = lane >> 4;
    const int t0 = chunk * CHK;
    const float ld = get_ld(logit);

    __shared__ unsigned short Qs[64][72];
    __shared__ unsigned short Ks[64][72];
    __shared__ unsigned short As[64][72];
    __shared__ unsigned short Kws[64][66];
    __shared__ unsigned short Vs[64][134];
    __shared__ float wks[64];
    __shared__ float cps[64];
    __shared__ float DIsh[64];

    if (tid < 64) {
        const float c = cpos(ld, t0 + tid);
        cps[tid] = c;
        wks[tid] = expf(cpos(ld, t0 + CHK - 1) - c);
        DIsh[tid] = 0.f;
    }
    __syncthreads();

    const unsigned short* Qg = Qb + ((size_t)b * LSEQ + t0) * MM;
    const unsigned short* Kg = Kb + ((size_t)b * LSEQ + t0) * MM;
#pragma unroll
    for (int l = 0; l < 2; ++l) {
        const int e = tid + l * 256;
        const int r = e >> 3, gq = e & 7;
        *(uint4*)&Qs[r][gq * 8] = *(const uint4*)(Qg + (size_t)e * 8);
        uint4 kraw = *(const uint4*)(Kg + (size_t)e * 8);
        *(uint4*)&Ks[r][gq * 8] = kraw;
        const float w = wks[r];
        const unsigned short* kp = (const unsigned short*)&kraw;
#pragma unroll
        for (int p = 0; p < 4; ++p) {
            ushort2 o;
            o.x = f2bf(w * bf2f(kp[2 * p]));
            o.y = f2bf(w * bf2f(kp[2 * p + 1]));
            *(ushort2*)&Kws[r][gq * 8 + 2 * p] = o;
        }
    }
    const unsigned short* Vg = Vb + ((size_t)b * LSEQ + t0) * DM + dg * 128;
#pragma unroll
    for (int l = 0; l < 4; ++l) {
        const int e = tid + l * 256;
        const int s = e >> 4, gg = e & 15;
        uint4 vr = *(const uint4*)(Vg + (size_t)s * DM + gg * 8);
        const unsigned short* vp = (const unsigned short*)&vr;
#pragma unroll
        for (int p = 0; p < 4; ++p) {
            ushort2 o;
            o.x = vp[2 * p]; o.y = vp[2 * p + 1];
            *(ushort2*)&Vs[s][gg * 8 + 2 * p] = o;
        }
    }
    __syncthreads();

    f32x4 sacc[2][2];
#pragma unroll
    for (int i = 0; i < 2; ++i)
#pragma unroll
        for (int j = 0; j < 2; ++j) sacc[i][j] = (f32x4)(0.f);
#pragma unroll
    for (int ks = 0; ks < 2; ++ks) {
        short8v qa[2], kb2[2];
#pragma unroll
        for (int mt = 0; mt < 2; ++mt)
            qa[mt] = *(const short8v*)&Qs[wr * 32 + mt * 16 + lr][ks * 32 + lk * 8];
#pragma unroll
        for (int nt = 0; nt < 2; ++nt)
            kb2[nt] = *(const short8v*)&Ks[wc * 32 + nt * 16 + lr][ks * 32 + lk * 8];
#pragma unroll
        for (int mt = 0; mt < 2; ++mt)
#pragma unroll
            for (int nt = 0; nt < 2; ++nt)
                sacc[mt][nt] = __builtin_amdgcn_mfma_f32_16x16x32_bf16(
                    qa[mt], kb2[nt], sacc[mt][nt], 0, 0, 0);
    }

#pragma unroll
    for (int mt = 0; mt < 2; ++mt) {
#pragma unroll
        for (int j = 0; j < 4; ++j) {
            const int t = wr * 32 + mt * 16 + lk * 4 + j;
            const float ct = cps[t];
            float rowpart = 0.f;
#pragma unroll
            for (int nt = 0; nt < 2; ++nt) {
                const int s = wc * 32 + nt * 16 + lr;
                float v = sacc[mt][nt][j];
                v = (s <= t) ? v * expf(ct - cps[s]) : 0.f;
                rowpart += v;
                As[t][s] = f2bf(v);
            }
            rowpart += __shfl_xor(rowpart, 1);
            rowpart += __shfl_xor(rowpart, 2);
            rowpart += __shfl_xor(rowpart, 4);
            rowpart += __shfl_xor(rowpart, 8);
            if (lr == 0) atomicAdd(&DIsh[t], rowpart);
        }
    }
    __syncthreads();

    if (dg == 0) {
        if (tid < 64) DI[(size_t)b * LSEQ + t0 + tid] = DIsh[tid];
        if (tid >= 64 && tid < 128) {
            const int m = tid - 64;
            float z = 0.f;
#pragma unroll
            for (int s = 0; s < 64; ++s) z += wks[s] * bf2f(Ks[s][m]);
            KZ[((size_t)b * NCHUNK + chunk) * MM + m] = z;
        }
    }

    f32x4 aO[2][4], aK[2][4];
#pragma unroll
    for (int i = 0; i < 2; ++i)
#pragma unroll
        for (int j = 0; j < 4; ++j) { aO[i][j] = (f32x4)(0.f); aK[i][j] = (f32x4)(0.f); }

#pragma unroll
    for (int ks = 0; ks < 2; ++ks) {
        short8v vf[4];
#pragma unroll
        for (int nt = 0; nt < 4; ++nt) {
            unsigned short* vp = (unsigned short*)&vf[nt];
            const int n = wc * 64 + nt * 16 + lr;
#pragma unroll
            for (int e = 0; e < 8; ++e)
                vp[e] = Vs[ks * 32 + lk * 8 + e][n];
        }
        short8v af2[2], kf2[2];
#pragma unroll
        for (int mt = 0; mt < 2; ++mt) {
            const int row = wr * 32 + mt * 16 + lr;
            af2[mt] = *(const short8v*)&As[row][ks * 32 + lk * 8];
            unsigned short* kp = (unsigned short*)&kf2[mt];
#pragma unroll
            for (int e = 0; e < 8; ++e)
                kp[e] = Kws[ks * 32 + lk * 8 + e][row];
        }
#pragma unroll
        for (int mt = 0; mt < 2; ++mt)
#pragma unroll
            for (int nt = 0; nt < 4; ++nt) {
                aO[mt][nt] = __builtin_amdgcn_mfma_f32_16x16x32_bf16(
                    af2[mt], vf[nt], aO[mt][nt], 0, 0, 0);
                aK[mt][nt] = __builtin_amdgcn_mfma_f32_16x16x32_bf16(
                    kf2[mt], vf[nt], aK[mt][nt], 0, 0, 0);
            }
    }

    unsigned short* OIb = OI + ((size_t)b * LSEQ + t0) * DM + dg * 128;
    unsigned short* KVb = KV + ((size_t)b * NCHUNK + chunk) * MM * DM + dg * 128;
#pragma unroll
    for (int mt = 0; mt < 2; ++mt)
#pragma unroll
        for (int nt = 0; nt < 4; ++nt) {
            const int col = wc * 64 + nt * 16 + lr;
#pragma unroll
            for (int j = 0; j < 4; ++j) {
                const int row = wr * 32 + mt * 16 + lk * 4 + j;
                OIb[(size_t)row * DM + col] = f2bf(aO[mt][nt][j]);
                KVb[(size_t)row * DM + col] = f2bf(aK[mt][nt][j]);
            }
        }
}

// ---- sequential scan over chunks (bf16 in/out, fp32 accum). grid 512x128 ----
__global__ __launch_bounds__(128) void state_scan(
    const unsigned short* __restrict__ KV, const float* __restrict__ KZ,
    const float* __restrict__ logit,
    unsigned short* __restrict__ SS, float* __restrict__ ZS)
{
    const int g = blockIdx.x * 128 + threadIdx.x;
    const int b = g >> 15;
    const int rem = g & 32767;
    const int m = rem >> 9;
    const int d = rem & 511;
    const float ld = get_ld(logit);
    const size_t base = (((size_t)b * NCHUNK) * MM + m) * DM + d;
    const size_t cstride = (size_t)MM * DM;

    float v[NCHUNK];
#pragma unroll
    for (int i = 0; i < NCHUNK; ++i) v[i] = bf2f(KV[base + (size_t)i * cstride]);

    float s = 0.f, cprev = 0.f;
#pragma unroll
    for (int i = 0; i < NCHUNK; ++i) {
        const float ce = cpos(ld, i * CHK + CHK - 1);
        const float lam = expf(ce - cprev);
        cprev = ce;
        SS[base + (size_t)i * cstride] = f2bf(s);
        s = lam * s + v[i];
    }
    if (d == 0) {
        float zs = 0.f;
        cprev = 0.f;
#pragma unroll
        for (int i = 0; i < NCHUNK; ++i) {
            const float ce = cpos(ld, i * CHK + CHK - 1);
            const float lam = expf(ce - cprev);
            cprev = ce;
            const int zi = (b * NCHUNK + i) * MM + m;
            ZS[zi] = zs;
            zs = lam * zs + KZ[zi];
        }
    }
}

// ---- fused inter-chunk combine + DEN + RMS norm -> bf16 (quarter-chunks) ----
// grid (NCHUNK, 4, NB): 256 blocks, 16 rows each
__global__ __launch_bounds__(256) void combine_rms(
    const unsigned short* __restrict__ Qb, const unsigned short* __restrict__ SSb,
    const float* __restrict__ ZS, const unsigned short* __restrict__ OI,
    const float* __restrict__ DI, const float* __restrict__ logit,
    const float* __restrict__ norm_w, unsigned short* __restrict__ NRM)
{
    const int chunk = blockIdx.x, quarter = blockIdx.y, b = blockIdx.z;
    const int tid = threadIdx.x;
    const int lane = tid & 63, w = tid >> 6;   // wave -> col block w*128
    const int lr = lane & 15, lk = lane >> 4;
    const int t0 = chunk * CHK;
    const int r0 = quarter * 16;
    const float ld = get_ld(logit);

    __shared__ unsigned short Qs[16][72];
    __shared__ unsigned short Ssh[64][514];   // strided u16 reads conflict-free
    __shared__ float wsh[512];
    __shared__ float gv[16], invden[16], xsq[16], rinv[16];

    // stage Q rows [t0+r0, +16)
    if (tid < 128) {
        const unsigned short* Qg = Qb + ((size_t)b * LSEQ + t0 + r0) * MM;
        const int r = tid >> 3, g8 = tid & 7;
        *(uint4*)&Qs[r][g8 * 8] = *(const uint4*)(Qg + (size_t)tid * 8);
    }
    // stage S_prev (64x512 bf16)
    {
        const unsigned short* Sg = SSb + ((size_t)(b * NCHUNK + chunk) * MM) * DM;
#pragma unroll
        for (int l = 0; l < 16; ++l) {
            const int e = tid + l * 256;
            const int m = e >> 6, g8 = e & 63;
            uint4 v = *(const uint4*)(Sg + (size_t)m * DM + g8 * 8);
            const unsigned short* vp = (const unsigned short*)&v;
#pragma unroll
            for (int p = 0; p < 4; ++p) {
                ushort2 o; o.x = vp[2 * p]; o.y = vp[2 * p + 1];
                *(ushort2*)&Ssh[m][g8 * 8 + 2 * p] = o;
            }
        }
    }
    wsh[tid] = norm_w[tid];
    wsh[tid + 256] = norm_w[tid + 256];
    if (tid < 16) {
        const float cprev = (chunk > 0) ? cpos(ld, t0 - 1) : 0.f;
        gv[tid] = expf(cpos(ld, t0 + r0 + tid) - cprev);
        xsq[tid] = 0.f;
    }
    __syncthreads();

    if (tid < 16) {
        const float* zp = ZS + ((size_t)b * NCHUNK + chunk) * MM;
        float a = 0.f;
#pragma unroll
        for (int m = 0; m < MM; ++m) a += bf2f(Qs[tid][m]) * zp[m];
        invden[tid] = 1.0f /
            (gv[tid] * a + DI[(size_t)b * LSEQ + t0 + r0 + tid] + 1e-6f);
    }

    // O_inter = Q(16x64) @ S_prev(64x512): wave w covers cols w*128..+128
    f32x4 acc[8];
#pragma unroll
    for (int j = 0; j < 8; ++j) acc[j] = (f32x4)(0.f);

#pragma unroll
    for (int ks = 0; ks < 2; ++ks) {
        short8v vf[8];
#pragma unroll
        for (int nt = 0; nt < 8; ++nt) {
            unsigned short* vp = (unsigned short*)&vf[nt];
            const int col = w * 128 + nt * 16 + lr;
#pragma unroll
            for (int e = 0; e < 8; ++e)
                vp[e] = Ssh[ks * 32 + lk * 8 + e][col];
        }
        short8v af = *(const short8v*)&Qs[lr][ks * 32 + lk * 8];
#pragma unroll
        for (int nt = 0; nt < 8; ++nt)
            acc[nt] = __builtin_amdgcn_mfma_f32_16x16x32_bf16(
                af, vf[nt], acc[nt], 0, 0, 0);
    }
    __syncthreads();   // invden visible

    const unsigned short* OIb = OI + ((size_t)b * LSEQ + t0 + r0) * DM;
#pragma unroll
    for (int j = 0; j < 4; ++j) {
        const int row = lk * 4 + j;
        const float g = gv[row];
        const float inv = invden[row];
        float part = 0.f;
#pragma unroll
        for (int nt = 0; nt < 8; ++nt) {
            const int col = w * 128 + nt * 16 + lr;
            float v = g * acc[nt][j] + bf2f(OIb[(size_t)row * DM + col]);
            float xx = v * inv;
            acc[nt][j] = xx;
            part += xx * xx;
        }
        part += __shfl_xor(part, 1);
        part += __shfl_xor(part, 2);
        part += __shfl_xor(part, 4);
        part += __shfl_xor(part, 8);
        if (lr == 0) atomicAdd(&xsq[row], part);
    }
    __syncthreads();
    if (tid < 16)
        rinv[tid] = 1.0f / sqrtf(xsq[tid] * (1.0f / (float)DM) + 1e-6f);
    __syncthreads();

    unsigned short* NRMc = NRM + ((size_t)b * LSEQ + t0 + r0) * DM;
#pragma unroll
    for (int j = 0; j < 4; ++j) {
        const int row = lk * 4 + j;
        const float r = rinv[row];
#pragma unroll
        for (int nt = 0; nt < 8; ++nt) {
            const int col = w * 128 + nt * 16 + lr;
            NRMc[(size_t)row * DM + col] = f2bf(acc[nt][j] * r * wsh[col]);
        }
    }
}

// ---- output GEMM: 64x128 tiles, grid (64,4) ----
__global__ __launch_bounds__(256) void gemm_out(
    const unsigned short* __restrict__ Xb, const unsigned short* __restrict__ Wb,
    float* __restrict__ C)
{
    __shared__ unsigned short As[64][40];
    __shared__ unsigned short Bs[128][40];
    const int brow = blockIdx.x * 64;
    const int bcol = blockIdx.y * 128;
    const int tid = threadIdx.x;
    const int lane = tid & 63, wid = tid >> 6;
    const int wr = wid >> 1, wc = wid & 1;
    const int lr = lane & 15, lk = lane >> 4;

    f32x4 acc[2][4];
#pragma unroll
    for (int i = 0; i < 2; ++i)
#pragma unroll
        for (int j = 0; j < 4; ++j) acc[i][j] = (f32x4)(0.f);

    for (int k0 = 0; k0 < DM; k0 += 32) {
        {
            const int r = tid >> 2, kg = tid & 3;
            *(uint4*)&As[r][kg * 8] =
                *(const uint4*)&Xb[(size_t)(brow + r) * DM + k0 + kg * 8];
        }
#pragma unroll
        for (int i = 0; i < 2; ++i) {
            int c = tid * 2 + i;
            int r = c >> 2, kg = c & 3;
            *(uint4*)&Bs[r][kg * 8] =
                *(const uint4*)&Wb[(size_t)(bcol + r) * DM + k0 + kg * 8];
        }
        __syncthreads();
        short8v af[2], bf[4];
#pragma unroll
        for (int mt = 0; mt < 2; ++mt)
            af[mt] = *(const short8v*)&As[wr * 32 + mt * 16 + lr][lk * 8];
#pragma unroll
        for (int nt = 0; nt < 4; ++nt)
            bf[nt] = *(const short8v*)&Bs[wc * 64 + nt * 16 + lr][lk * 8];
#pragma unroll
        for (int mt = 0; mt < 2; ++mt)
#pragma unroll
            for (int nt = 0; nt < 4; ++nt)
                acc[mt][nt] = __builtin_amdgcn_mfma_f32_16x16x32_bf16(
                    af[mt], bf[nt], acc[mt][nt], 0, 0, 0);
        __syncthreads();
    }

#pragma unroll
    for (int mt = 0; mt < 2; ++mt)
#pragma unroll
        for (int nt = 0; nt < 4; ++nt) {
            const int row0 = brow + wr * 32 + mt * 16 + lk * 4;
            const int col = bcol + wc * 64 + nt * 16 + lr;
#pragma unroll
            for (int j = 0; j < 4; ++j)
                C[(size_t)(row0 + j) * DM + col] = acc[mt][nt][j];
        }
}

extern "C" void kernel_launch(void* const* d_in, const int* in_sizes, int n_in,
                              void* d_out, int out_size, void* d_ws, size_t ws_size,
                              hipStream_t stream) {
    const float* x      = (const float*)d_in[0];
    const float* W_q    = (const float*)d_in[1];
    const float* W_k    = (const float*)d_in[2];
    const float* W_v    = (const float*)d_in[3];
    const float* W_o    = (const float*)d_in[4];
    const float* logit  = (const float*)d_in[5];
    const float* norm_w = (const float*)d_in[6];
    float* out = (float*)d_out;

    const size_t BLM = (size_t)NB * LSEQ * MM;          // 262144
    const size_t BLD = (size_t)NB * LSEQ * DM;          // 2097152
    const size_t BL  = (size_t)NB * LSEQ;               // 4096
    const size_t BNCMD = (size_t)NB * NCHUNK * MM * DM; // 2097152
    const size_t BNCM  = (size_t)NB * NCHUNK * MM;      // 4096
    const size_t WSZ = (size_t)DM * DM;                 // 262144

    float* ws = (float*)d_ws;
    float* DIp = ws;                       // BL
    float* KZp = DIp + BL;                 // BNCM
    float* ZSp = KZp + BNCM;               // BNCM
    unsigned short* OIb  = (unsigned short*)(ZSp + BNCM);  // BLD
    unsigned short* KVb  = OIb + BLD;      // BNCMD
    unsigned short* SSb  = KVb + BNCMD;    // BNCMD
    unsigned short* Wob16 = SSb + BNCMD;   // WSZ
    unsigned short* Qb16 = Wob16 + WSZ;    // BLM
    unsigned short* Kb16 = Qb16 + BLM;     // BLM
    unsigned short* Vb16 = Kb16 + BLM;     // BLD
    unsigned short* NRMb = Vb16 + BLD;     // BLD

    // 1. fused QKV projection (+ W_o cvt)
    gemm_proj<<<dim3(64, 6), 256, 0, stream>>>(x, W_q, W_k, W_v, W_o,
                                               Qb16, Kb16, Vb16, Wob16);
    // 2. intra-chunk attention + summaries (bf16 OI/KV out)
    chunk_local_mfma<<<dim3(NCHUNK, 4, NB), 256, 0, stream>>>(
        Qb16, Kb16, Vb16, logit, OIb, DIp, KVb, KZp);
    // 3. sequential state scan (bf16 in/out)
    state_scan<<<dim3(512), 128, 0, stream>>>(KVb, KZp, logit, SSb, ZSp);
    // 4. combine + DEN + RMS -> bf16 (quarter-chunks, 256 blocks)
    combine_rms<<<dim3(NCHUNK, 4, NB), 256, 0, stream>>>(
        Qb16, SSb, ZSp, OIb, DIp, logit, norm_w, NRMb);
    // 5. output projection
    gemm_out<<<dim3(64, 4), 256, 0, stream>>>(NRMb, Wob16, out);
}

// Round 10
// 57.067 us; speedup vs baseline: 1.0836x; 1.0836x over previous
//
#include <hip/hip_runtime.h>
#include <math.h>

#define NB 2
#define LSEQ 2048
#define DM 512
#define MM 64
#define CHK 64
#define NCHUNK 32

typedef __attribute__((ext_vector_type(8))) short short8v;
typedef __attribute__((ext_vector_type(4))) float f32x4;

__device__ __forceinline__ float get_ld(const float* __restrict__ logit) {
    float lg = *logit;
    float dec = 1.0f / (1.0f + expf(-lg));
    dec = fmaxf(dec, 1e-6f);
    return logf(dec);
}
__device__ __forceinline__ float cpos(float ld, int t) {
    return fminf(fmaxf(ld * (float)t, -20.0f), 20.0f);
}
__device__ __forceinline__ float phi_fn(float v) {
    return v > 0.0f ? v + 1.0f : expf(v);
}
__device__ __forceinline__ unsigned short f2bf(float f) {
    unsigned int u = __float_as_uint(f);
    u += 0x7FFFu + ((u >> 16) & 1u);   // RNE
    return (unsigned short)(u >> 16);
}
__device__ __forceinline__ float bf2f(unsigned short h) {
    unsigned int u = ((unsigned int)h) << 16;
    return __uint_as_float(u);
}
// load 8 f32, convert to 8 bf16 packed in a uint4
__device__ __forceinline__ uint4 cvt8(const float* __restrict__ p) {
    float4 a = *(const float4*)p;
    float4 b = *(const float4*)(p + 4);
    union { unsigned short u[8]; uint4 v; } r;
    r.u[0] = f2bf(a.x); r.u[1] = f2bf(a.y); r.u[2] = f2bf(a.z); r.u[3] = f2bf(a.w);
    r.u[4] = f2bf(b.x); r.u[5] = f2bf(b.y); r.u[6] = f2bf(b.z); r.u[7] = f2bf(b.w);
    return r.v;
}

// ---- fused QKV projection (cvt-on-the-fly) + W_o cvt slice, 512 threads ----
// grid (64, 6): y=0 QK (cols = Wq|Wk), y=1..4 V col slices, y=5 W_o cvt
__global__ __launch_bounds__(512) void gemm_proj(
    const float* __restrict__ x, const float* __restrict__ W_q,
    const float* __restrict__ W_k, const float* __restrict__ W_v,
    const float* __restrict__ W_o,
    unsigned short* __restrict__ Qh, unsigned short* __restrict__ Kh,
    unsigned short* __restrict__ Vh, unsigned short* __restrict__ Wob)
{
    const int cb = blockIdx.y;
    const int tid = threadIdx.x;
    if (cb == 5) {  // W_o -> bf16 (64 blocks x 512 thr x 2 float4)
        const int stride = 64 * 512;
#pragma unroll
        for (int it = 0; it < 2; ++it) {
            int i = blockIdx.x * 512 + tid + it * stride;
            float4 v = ((const float4*)W_o)[i];
            ushort4 o;
            o.x = f2bf(v.x); o.y = f2bf(v.y); o.z = f2bf(v.z); o.w = f2bf(v.w);
            ((ushort4*)Wob)[i] = o;
        }
        return;
    }

    __shared__ unsigned short As[64][40];
    __shared__ unsigned short Bs[128][40];
    const int brow = blockIdx.x * 64;
    const int lane = tid & 63, w = tid >> 6;     // 8 waves
    const int wr = w >> 2, wc = w & 3;           // 2x4: rows wr*32, cols wc*32
    const int lr = lane & 15, lk = lane >> 4;

    f32x4 acc[2][2];
#pragma unroll
    for (int i = 0; i < 2; ++i)
#pragma unroll
        for (int j = 0; j < 2; ++j) acc[i][j] = (f32x4)(0.f);

    for (int k0 = 0; k0 < DM; k0 += 32) {
        if (tid < 256) {   // A tile: 64x32 = 256 groups of 8
            const int r = tid >> 2, kg = tid & 3;
            *(uint4*)&As[r][kg * 8] = cvt8(&x[(size_t)(brow + r) * DM + k0 + kg * 8]);
        }
        {   // B tile: 128x32 = 512 groups
            const int r = tid >> 2, kg = tid & 3;
            const float* wsrc;
            if (cb == 0)
                wsrc = (r < 64) ? &W_q[(size_t)r * DM + k0 + kg * 8]
                                : &W_k[(size_t)(r - 64) * DM + k0 + kg * 8];
            else
                wsrc = &W_v[(size_t)((cb - 1) * 128 + r) * DM + k0 + kg * 8];
            *(uint4*)&Bs[r][kg * 8] = cvt8(wsrc);
        }
        __syncthreads();
        short8v af[2], bf[2];
#pragma unroll
        for (int mt = 0; mt < 2; ++mt)
            af[mt] = *(const short8v*)&As[wr * 32 + mt * 16 + lr][lk * 8];
#pragma unroll
        for (int nt = 0; nt < 2; ++nt)
            bf[nt] = *(const short8v*)&Bs[wc * 32 + nt * 16 + lr][lk * 8];
#pragma unroll
        for (int mt = 0; mt < 2; ++mt)
#pragma unroll
            for (int nt = 0; nt < 2; ++nt)
                acc[mt][nt] = __builtin_amdgcn_mfma_f32_16x16x32_bf16(
                    af[mt], bf[nt], acc[mt][nt], 0, 0, 0);
        __syncthreads();
    }

#pragma unroll
    for (int mt = 0; mt < 2; ++mt)
#pragma unroll
        for (int nt = 0; nt < 2; ++nt) {
            const int col = wc * 32 + nt * 16 + lr;
#pragma unroll
            for (int j = 0; j < 4; ++j) {
                const int row = brow + wr * 32 + mt * 16 + lk * 4 + j;
                float v = acc[mt][nt][j];
                if (cb == 0) {
                    v = phi_fn(v);
                    if (col < 64)
                        Qh[(size_t)row * MM + col] = f2bf(v * 0.125f);
                    else
                        Kh[(size_t)row * MM + (col - 64)] = f2bf(v);
                } else {
                    Vh[(size_t)row * DM + (cb - 1) * 128 + col] = f2bf(v);
                }
            }
        }
}

// ---- intra-chunk attention + summaries, 512 threads, bf16 OI/KV out ----
__global__ __launch_bounds__(512) void chunk_local_mfma(
    const unsigned short* __restrict__ Qb, const unsigned short* __restrict__ Kb,
    const unsigned short* __restrict__ Vb, const float* __restrict__ logit,
    unsigned short* __restrict__ OI, float* __restrict__ DI,
    unsigned short* __restrict__ KV, float* __restrict__ KZ)
{
    const int chunk = blockIdx.x, dg = blockIdx.y, b = blockIdx.z;
    const int tid = threadIdx.x;
    const int lane = tid & 63, w = tid >> 6;    // 8 waves
    const int lr = lane & 15, lk = lane >> 4;
    const int t0 = chunk * CHK;
    const float ld = get_ld(logit);

    __shared__ unsigned short Qs[64][72];
    __shared__ unsigned short Ks[64][72];
    __shared__ unsigned short As[64][72];
    __shared__ unsigned short Kws[64][66];
    __shared__ unsigned short Vs[64][134];
    __shared__ float wks[64];
    __shared__ float cps[64];
    __shared__ float DIsh[64];

    if (tid < 64) {
        const float c = cpos(ld, t0 + tid);
        cps[tid] = c;
        wks[tid] = expf(cpos(ld, t0 + CHK - 1) - c);
        DIsh[tid] = 0.f;
    }
    __syncthreads();

    // stage Q, K, Kws: 512 groups of 8
    {
        const unsigned short* Qg = Qb + ((size_t)b * LSEQ + t0) * MM;
        const unsigned short* Kg = Kb + ((size_t)b * LSEQ + t0) * MM;
        const int r = tid >> 3, gq = tid & 7;
        *(uint4*)&Qs[r][gq * 8] = *(const uint4*)(Qg + (size_t)tid * 8);
        uint4 kraw = *(const uint4*)(Kg + (size_t)tid * 8);
        *(uint4*)&Ks[r][gq * 8] = kraw;
        const float wv = wks[r];
        const unsigned short* kp = (const unsigned short*)&kraw;
#pragma unroll
        for (int p = 0; p < 4; ++p) {
            ushort2 o;
            o.x = f2bf(wv * bf2f(kp[2 * p]));
            o.y = f2bf(wv * bf2f(kp[2 * p + 1]));
            *(ushort2*)&Kws[r][gq * 8 + 2 * p] = o;
        }
    }
    // stage V slice: 1024 groups of 8
    {
        const unsigned short* Vg = Vb + ((size_t)b * LSEQ + t0) * DM + dg * 128;
#pragma unroll
        for (int l = 0; l < 2; ++l) {
            const int e = tid + l * 512;
            const int s = e >> 4, gg = e & 15;
            uint4 vr = *(const uint4*)(Vg + (size_t)s * DM + gg * 8);
            const unsigned short* vp = (const unsigned short*)&vr;
#pragma unroll
            for (int p = 0; p < 4; ++p) {
                ushort2 o;
                o.x = vp[2 * p]; o.y = vp[2 * p + 1];
                *(ushort2*)&Vs[s][gg * 8 + 2 * p] = o;
            }
        }
    }
    __syncthreads();

    // S = Q K^T: 8 waves, each 16 rows x 32 cols
    {
        const int wr2 = w >> 1, wc2 = w & 1;
        f32x4 sacc[2];
        sacc[0] = (f32x4)(0.f); sacc[1] = (f32x4)(0.f);
#pragma unroll
        for (int ks = 0; ks < 2; ++ks) {
            short8v qa = *(const short8v*)&Qs[wr2 * 16 + lr][ks * 32 + lk * 8];
            short8v kb2[2];
#pragma unroll
            for (int nt = 0; nt < 2; ++nt)
                kb2[nt] = *(const short8v*)&Ks[wc2 * 32 + nt * 16 + lr][ks * 32 + lk * 8];
#pragma unroll
            for (int nt = 0; nt < 2; ++nt)
                sacc[nt] = __builtin_amdgcn_mfma_f32_16x16x32_bf16(
                    qa, kb2[nt], sacc[nt], 0, 0, 0);
        }
#pragma unroll
        for (int j = 0; j < 4; ++j) {
            const int t = wr2 * 16 + lk * 4 + j;
            const float ct = cps[t];
            float rowpart = 0.f;
#pragma unroll
            for (int nt = 0; nt < 2; ++nt) {
                const int s = wc2 * 32 + nt * 16 + lr;
                float v = sacc[nt][j];
                v = (s <= t) ? v * expf(ct - cps[s]) : 0.f;
                rowpart += v;
                As[t][s] = f2bf(v);
            }
            rowpart += __shfl_xor(rowpart, 1);
            rowpart += __shfl_xor(rowpart, 2);
            rowpart += __shfl_xor(rowpart, 4);
            rowpart += __shfl_xor(rowpart, 8);
            if (lr == 0) atomicAdd(&DIsh[t], rowpart);
        }
    }
    __syncthreads();

    if (dg == 0) {
        if (tid < 64) DI[(size_t)b * LSEQ + t0 + tid] = DIsh[tid];
        if (tid >= 64 && tid < 128) {
            const int m = tid - 64;
            float z = 0.f;
#pragma unroll
            for (int s = 0; s < 64; ++s) z += wks[s] * bf2f(Ks[s][m]);
            KZ[((size_t)b * NCHUNK + chunk) * MM + m] = z;
        }
    }

    // waves 0-3: O = A.V ; waves 4-7: KV = Kw^T.V  (each 32 rows x 64 cols)
    {
        const int isKV = w >> 2;
        const int w2 = w & 3;
        const int wr = w2 >> 1, wc = w2 & 1;

        f32x4 a2[2][4];
#pragma unroll
        for (int i = 0; i < 2; ++i)
#pragma unroll
            for (int j = 0; j < 4; ++j) a2[i][j] = (f32x4)(0.f);

#pragma unroll
        for (int ks = 0; ks < 2; ++ks) {
            short8v vf[4];
#pragma unroll
            for (int nt = 0; nt < 4; ++nt) {
                unsigned short* vp = (unsigned short*)&vf[nt];
                const int n = wc * 64 + nt * 16 + lr;
#pragma unroll
                for (int e = 0; e < 8; ++e)
                    vp[e] = Vs[ks * 32 + lk * 8 + e][n];
            }
            short8v mf[2];
#pragma unroll
            for (int mt = 0; mt < 2; ++mt) {
                const int row = wr * 32 + mt * 16 + lr;
                if (!isKV) {
                    mf[mt] = *(const short8v*)&As[row][ks * 32 + lk * 8];
                } else {
                    unsigned short* kp = (unsigned short*)&mf[mt];
#pragma unroll
                    for (int e = 0; e < 8; ++e)
                        kp[e] = Kws[ks * 32 + lk * 8 + e][row];
                }
            }
#pragma unroll
            for (int mt = 0; mt < 2; ++mt)
#pragma unroll
                for (int nt = 0; nt < 4; ++nt)
                    a2[mt][nt] = __builtin_amdgcn_mfma_f32_16x16x32_bf16(
                        mf[mt], vf[nt], a2[mt][nt], 0, 0, 0);
        }

        if (!isKV) {
            unsigned short* OIb = OI + ((size_t)b * LSEQ + t0) * DM + dg * 128;
#pragma unroll
            for (int mt = 0; mt < 2; ++mt)
#pragma unroll
                for (int nt = 0; nt < 4; ++nt) {
                    const int col = wc * 64 + nt * 16 + lr;
#pragma unroll
                    for (int j = 0; j < 4; ++j) {
                        const int row = wr * 32 + mt * 16 + lk * 4 + j;
                        OIb[(size_t)row * DM + col] = f2bf(a2[mt][nt][j]);
                    }
                }
        } else {
            unsigned short* KVb = KV + ((size_t)b * NCHUNK + chunk) * MM * DM + dg * 128;
#pragma unroll
            for (int mt = 0; mt < 2; ++mt)
#pragma unroll
                for (int nt = 0; nt < 4; ++nt) {
                    const int col = wc * 64 + nt * 16 + lr;
#pragma unroll
                    for (int j = 0; j < 4; ++j) {
                        const int row = wr * 32 + mt * 16 + lk * 4 + j;
                        KVb[(size_t)row * DM + col] = f2bf(a2[mt][nt][j]);
                    }
                }
        }
    }
}

// ---- sequential scan over chunks (bf16 in/out, fp32 accum). grid 512x128 ----
__global__ __launch_bounds__(128) void state_scan(
    const unsigned short* __restrict__ KV, const float* __restrict__ KZ,
    const float* __restrict__ logit,
    unsigned short* __restrict__ SS, float* __restrict__ ZS)
{
    const int g = blockIdx.x * 128 + threadIdx.x;
    const int b = g >> 15;
    const int rem = g & 32767;
    const int m = rem >> 9;
    const int d = rem & 511;
    const float ld = get_ld(logit);
    const size_t base = (((size_t)b * NCHUNK) * MM + m) * DM + d;
    const size_t cstride = (size_t)MM * DM;

    float v[NCHUNK];
#pragma unroll
    for (int i = 0; i < NCHUNK; ++i) v[i] = bf2f(KV[base + (size_t)i * cstride]);

    float s = 0.f, cprev = 0.f;
#pragma unroll
    for (int i = 0; i < NCHUNK; ++i) {
        const float ce = cpos(ld, i * CHK + CHK - 1);
        const float lam = expf(ce - cprev);
        cprev = ce;
        SS[base + (size_t)i * cstride] = f2bf(s);
        s = lam * s + v[i];
    }
    if (d == 0) {
        float zs = 0.f;
        cprev = 0.f;
#pragma unroll
        for (int i = 0; i < NCHUNK; ++i) {
            const float ce = cpos(ld, i * CHK + CHK - 1);
            const float lam = expf(ce - cprev);
            cprev = ce;
            const int zi = (b * NCHUNK + i) * MM + m;
            ZS[zi] = zs;
            zs = lam * zs + KZ[zi];
        }
    }
}

// ---- fused combine + DEN + RMS -> bf16, 512 threads, quarter-chunks ----
// grid (NCHUNK, 4, NB): 256 blocks, 16 rows each; 8 waves x 64-col slices
__global__ __launch_bounds__(512) void combine_rms(
    const unsigned short* __restrict__ Qb, const unsigned short* __restrict__ SSb,
    const float* __restrict__ ZS, const unsigned short* __restrict__ OI,
    const float* __restrict__ DI, const float* __restrict__ logit,
    const float* __restrict__ norm_w, unsigned short* __restrict__ NRM)
{
    const int chunk = blockIdx.x, quarter = blockIdx.y, b = blockIdx.z;
    const int tid = threadIdx.x;
    const int lane = tid & 63, w = tid >> 6;   // wave -> col block w*64
    const int lr = lane & 15, lk = lane >> 4;
    const int t0 = chunk * CHK;
    const int r0 = quarter * 16;
    const float ld = get_ld(logit);

    __shared__ unsigned short Qs[16][72];
    __shared__ unsigned short Ssh[64][514];   // strided u16 reads conflict-free
    __shared__ float wsh[512];
    __shared__ float gv[16], invden[16], xsq[16], rinv[16];

    // stage Q rows [t0+r0, +16): 128 groups of 8
    if (tid < 128) {
        const unsigned short* Qg = Qb + ((size_t)b * LSEQ + t0 + r0) * MM;
        const int r = tid >> 3, g8 = tid & 7;
        *(uint4*)&Qs[r][g8 * 8] = *(const uint4*)(Qg + (size_t)tid * 8);
    }
    // stage S_prev (64x512 bf16): 4096 groups of 8
    {
        const unsigned short* Sg = SSb + ((size_t)(b * NCHUNK + chunk) * MM) * DM;
#pragma unroll
        for (int l = 0; l < 8; ++l) {
            const int e = tid + l * 512;
            const int m = e >> 6, g8 = e & 63;
            uint4 v = *(const uint4*)(Sg + (size_t)m * DM + g8 * 8);
            const unsigned short* vp = (const unsigned short*)&v;
#pragma unroll
            for (int p = 0; p < 4; ++p) {
                ushort2 o; o.x = vp[2 * p]; o.y = vp[2 * p + 1];
                *(ushort2*)&Ssh[m][g8 * 8 + 2 * p] = o;
            }
        }
    }
    wsh[tid] = norm_w[tid];
    if (tid < 16) {
        const float cprev = (chunk > 0) ? cpos(ld, t0 - 1) : 0.f;
        gv[tid] = expf(cpos(ld, t0 + r0 + tid) - cprev);
        xsq[tid] = 0.f;
    }
    __syncthreads();

    if (tid < 16) {
        const float* zp = ZS + ((size_t)b * NCHUNK + chunk) * MM;
        float a = 0.f;
#pragma unroll
        for (int m = 0; m < MM; ++m) a += bf2f(Qs[tid][m]) * zp[m];
        invden[tid] = 1.0f /
            (gv[tid] * a + DI[(size_t)b * LSEQ + t0 + r0 + tid] + 1e-6f);
    }

    // O_inter = Q(16x64) @ S_prev(64x512): wave w covers cols w*64..+64
    f32x4 acc[4];
#pragma unroll
    for (int j = 0; j < 4; ++j) acc[j] = (f32x4)(0.f);

#pragma unroll
    for (int ks = 0; ks < 2; ++ks) {
        short8v vf[4];
#pragma unroll
        for (int nt = 0; nt < 4; ++nt) {
            unsigned short* vp = (unsigned short*)&vf[nt];
            const int col = w * 64 + nt * 16 + lr;
#pragma unroll
            for (int e = 0; e < 8; ++e)
                vp[e] = Ssh[ks * 32 + lk * 8 + e][col];
        }
        short8v af = *(const short8v*)&Qs[lr][ks * 32 + lk * 8];
#pragma unroll
        for (int nt = 0; nt < 4; ++nt)
            acc[nt] = __builtin_amdgcn_mfma_f32_16x16x32_bf16(
                af, vf[nt], acc[nt], 0, 0, 0);
    }
    __syncthreads();   // invden visible

    const unsigned short* OIb = OI + ((size_t)b * LSEQ + t0 + r0) * DM;
#pragma unroll
    for (int j = 0; j < 4; ++j) {
        const int row = lk * 4 + j;
        const float g = gv[row];
        const float inv = invden[row];
        float part = 0.f;
#pragma unroll
        for (int nt = 0; nt < 4; ++nt) {
            const int col = w * 64 + nt * 16 + lr;
            float v = g * acc[nt][j] + bf2f(OIb[(size_t)row * DM + col]);
            float xx = v * inv;
            acc[nt][j] = xx;
            part += xx * xx;
        }
        part += __shfl_xor(part, 1);
        part += __shfl_xor(part, 2);
        part += __shfl_xor(part, 4);
        part += __shfl_xor(part, 8);
        if (lr == 0) atomicAdd(&xsq[row], part);
    }
    __syncthreads();
    if (tid < 16)
        rinv[tid] = 1.0f / sqrtf(xsq[tid] * (1.0f / (float)DM) + 1e-6f);
    __syncthreads();

    unsigned short* NRMc = NRM + ((size_t)b * LSEQ + t0 + r0) * DM;
#pragma unroll
    for (int j = 0; j < 4; ++j) {
        const int row = lk * 4 + j;
        const float r = rinv[row];
#pragma unroll
        for (int nt = 0; nt < 4; ++nt) {
            const int col = w * 64 + nt * 16 + lr;
            NRMc[(size_t)row * DM + col] = f2bf(acc[nt][j] * r * wsh[col]);
        }
    }
}

// ---- output GEMM: 64x128 tiles, 512 threads, grid (64,4) ----
__global__ __launch_bounds__(512) void gemm_out(
    const unsigned short* __restrict__ Xb, const unsigned short* __restrict__ Wb,
    float* __restrict__ C)
{
    __shared__ unsigned short As[64][40];
    __shared__ unsigned short Bs[128][40];
    const int brow = blockIdx.x * 64;
    const int bcol = blockIdx.y * 128;
    const int tid = threadIdx.x;
    const int lane = tid & 63, w = tid >> 6;    // 8 waves
    const int wr = w >> 2, wc = w & 3;          // rows wr*32, cols wc*32
    const int lr = lane & 15, lk = lane >> 4;

    f32x4 acc[2][2];
#pragma unroll
    for (int i = 0; i < 2; ++i)
#pragma unroll
        for (int j = 0; j < 2; ++j) acc[i][j] = (f32x4)(0.f);

    for (int k0 = 0; k0 < DM; k0 += 32) {
        if (tid < 256) {
            const int r = tid >> 2, kg = tid & 3;
            *(uint4*)&As[r][kg * 8] =
                *(const uint4*)&Xb[(size_t)(brow + r) * DM + k0 + kg * 8];
        }
        {
            const int r = tid >> 2, kg = tid & 3;
            *(uint4*)&Bs[r][kg * 8] =
                *(const uint4*)&Wb[(size_t)(bcol + r) * DM + k0 + kg * 8];
        }
        __syncthreads();
        short8v af[2], bf[2];
#pragma unroll
        for (int mt = 0; mt < 2; ++mt)
            af[mt] = *(const short8v*)&As[wr * 32 + mt * 16 + lr][lk * 8];
#pragma unroll
        for (int nt = 0; nt < 2; ++nt)
            bf[nt] = *(const short8v*)&Bs[wc * 32 + nt * 16 + lr][lk * 8];
#pragma unroll
        for (int mt = 0; mt < 2; ++mt)
#pragma unroll
            for (int nt = 0; nt < 2; ++nt)
                acc[mt][nt] = __builtin_amdgcn_mfma_f32_16x16x32_bf16(
                    af[mt], bf[nt], acc[mt][nt], 0, 0, 0);
        __syncthreads();
    }

#pragma unroll
    for (int mt = 0; mt < 2; ++mt)
#pragma unroll
        for (int nt = 0; nt < 2; ++nt) {
            const int row0 = brow + wr * 32 + mt * 16 + lk * 4;
            const int col = bcol + wc * 32 + nt * 16 + lr;
#pragma unroll
            for (int j = 0; j < 4; ++j)
                C[(size_t)(row0 + j) * DM + col] = acc[mt][nt][j];
        }
}

extern "C" void kernel_launch(void* const* d_in, const int* in_sizes, int n_in,
                              void* d_out, int out_size, void* d_ws, size_t ws_size,
                              hipStream_t stream) {
    const float* x      = (const float*)d_in[0];
    const float* W_q    = (const float*)d_in[1];
    const float* W_k    = (const float*)d_in[2];
    const float* W_v    = (const float*)d_in[3];
    const float* W_o    = (const float*)d_in[4];
    const float* logit  = (const float*)d_in[5];
    const float* norm_w = (const float*)d_in[6];
    float* out = (float*)d_out;

    const size_t BLM = (size_t)NB * LSEQ * MM;          // 262144
    const size_t BLD = (size_t)NB * LSEQ * DM;          // 2097152
    const size_t BL  = (size_t)NB * LSEQ;               // 4096
    const size_t BNCMD = (size_t)NB * NCHUNK * MM * DM; // 2097152
    const size_t BNCM  = (size_t)NB * NCHUNK * MM;      // 4096
    const size_t WSZ = (size_t)DM * DM;                 // 262144

    float* ws = (float*)d_ws;
    float* DIp = ws;                       // BL
    float* KZp = DIp + BL;                 // BNCM
    float* ZSp = KZp + BNCM;               // BNCM
    unsigned short* OIb  = (unsigned short*)(ZSp + BNCM);  // BLD
    unsigned short* KVb  = OIb + BLD;      // BNCMD
    unsigned short* SSb  = KVb + BNCMD;    // BNCMD
    unsigned short* Wob16 = SSb + BNCMD;   // WSZ
    unsigned short* Qb16 = Wob16 + WSZ;    // BLM
    unsigned short* Kb16 = Qb16 + BLM;     // BLM
    unsigned short* Vb16 = Kb16 + BLM;     // BLD
    unsigned short* NRMb = Vb16 + BLD;     // BLD

    // 1. fused QKV projection (+ W_o cvt)
    gemm_proj<<<dim3(64, 6), 512, 0, stream>>>(x, W_q, W_k, W_v, W_o,
                                               Qb16, Kb16, Vb16, Wob16);
    // 2. intra-chunk attention + summaries (bf16 OI/KV out)
    chunk_local_mfma<<<dim3(NCHUNK, 4, NB), 512, 0, stream>>>(
        Qb16, Kb16, Vb16, logit, OIb, DIp, KVb, KZp);
    // 3. sequential state scan (bf16 in/out)
    state_scan<<<dim3(512), 128, 0, stream>>>(KVb, KZp, logit, SSb, ZSp);
    // 4. combine + DEN + RMS -> bf16 (quarter-chunks, 256 blocks, 8 waves)
    combine_rms<<<dim3(NCHUNK, 4, NB), 512, 0, stream>>>(
        Qb16, SSb, ZSp, OIb, DIp, logit, norm_w, NRMb);
    // 5. output projection (8 waves)
    gemm_out<<<dim3(64, 4), 512, 0, stream>>>(NRMb, Wob16, out);
}

// Round 11
// 55.433 us; speedup vs baseline: 1.1155x; 1.0295x over previous
//
#include <hip/hip_runtime.h>
#include <math.h>

#define NB 2
#define LSEQ 2048
#define DM 512
#define MM 64
#define CHK 64
#define NCHUNK 32

typedef __attribute__((ext_vector_type(8))) short short8v;
typedef __attribute__((ext_vector_type(4))) float f32x4;

__device__ __forceinline__ float get_ld(const float* __restrict__ logit) {
    float lg = *logit;
    float dec = 1.0f / (1.0f + expf(-lg));
    dec = fmaxf(dec, 1e-6f);
    return logf(dec);
}
__device__ __forceinline__ float cpos(float ld, int t) {
    return fminf(fmaxf(ld * (float)t, -20.0f), 20.0f);
}
__device__ __forceinline__ float phi_fn(float v) {
    return v > 0.0f ? v + 1.0f : expf(v);
}
__device__ __forceinline__ unsigned short f2bf(float f) {
    unsigned int u = __float_as_uint(f);
    u += 0x7FFFu + ((u >> 16) & 1u);   // RNE
    return (unsigned short)(u >> 16);
}
__device__ __forceinline__ float bf2f(unsigned short h) {
    unsigned int u = ((unsigned int)h) << 16;
    return __uint_as_float(u);
}
// load 8 f32, convert to 8 bf16 packed in a uint4
__device__ __forceinline__ uint4 cvt8(const float* __restrict__ p) {
    float4 a = *(const float4*)p;
    float4 b = *(const float4*)(p + 4);
    union { unsigned short u[8]; uint4 v; } r;
    r.u[0] = f2bf(a.x); r.u[1] = f2bf(a.y); r.u[2] = f2bf(a.z); r.u[3] = f2bf(a.w);
    r.u[4] = f2bf(b.x); r.u[5] = f2bf(b.y); r.u[6] = f2bf(b.z); r.u[7] = f2bf(b.w);
    return r.v;
}

// ---- fused QKV projection (cvt-on-the-fly) + W_o cvt slice, 512 threads ----
// grid (64, 6): y=0 QK (cols = Wq|Wk), y=1..4 V col slices, y=5 W_o cvt
__global__ __launch_bounds__(512) void gemm_proj(
    const float* __restrict__ x, const float* __restrict__ W_q,
    const float* __restrict__ W_k, const float* __restrict__ W_v,
    const float* __restrict__ W_o,
    unsigned short* __restrict__ Qh, unsigned short* __restrict__ Kh,
    unsigned short* __restrict__ Vh, unsigned short* __restrict__ Wob)
{
    const int cb = blockIdx.y;
    const int tid = threadIdx.x;
    if (cb == 5) {  // W_o -> bf16 (64 blocks x 512 thr x 2 float4)
        const int stride = 64 * 512;
#pragma unroll
        for (int it = 0; it < 2; ++it) {
            int i = blockIdx.x * 512 + tid + it * stride;
            float4 v = ((const float4*)W_o)[i];
            ushort4 o;
            o.x = f2bf(v.x); o.y = f2bf(v.y); o.z = f2bf(v.z); o.w = f2bf(v.w);
            ((ushort4*)Wob)[i] = o;
        }
        return;
    }

    __shared__ unsigned short As[64][40];
    __shared__ unsigned short Bs[128][40];
    const int brow = blockIdx.x * 64;
    const int lane = tid & 63, w = tid >> 6;     // 8 waves
    const int wr = w >> 2, wc = w & 3;           // 2x4: rows wr*32, cols wc*32
    const int lr = lane & 15, lk = lane >> 4;

    f32x4 acc[2][2];
#pragma unroll
    for (int i = 0; i < 2; ++i)
#pragma unroll
        for (int j = 0; j < 2; ++j) acc[i][j] = (f32x4)(0.f);

    for (int k0 = 0; k0 < DM; k0 += 32) {
        if (tid < 256) {   // A tile: 64x32 = 256 groups of 8
            const int r = tid >> 2, kg = tid & 3;
            *(uint4*)&As[r][kg * 8] = cvt8(&x[(size_t)(brow + r) * DM + k0 + kg * 8]);
        }
        {   // B tile: 128x32 = 512 groups
            const int r = tid >> 2, kg = tid & 3;
            const float* wsrc;
            if (cb == 0)
                wsrc = (r < 64) ? &W_q[(size_t)r * DM + k0 + kg * 8]
                                : &W_k[(size_t)(r - 64) * DM + k0 + kg * 8];
            else
                wsrc = &W_v[(size_t)((cb - 1) * 128 + r) * DM + k0 + kg * 8];
            *(uint4*)&Bs[r][kg * 8] = cvt8(wsrc);
        }
        __syncthreads();
        short8v af[2], bf[2];
#pragma unroll
        for (int mt = 0; mt < 2; ++mt)
            af[mt] = *(const short8v*)&As[wr * 32 + mt * 16 + lr][lk * 8];
#pragma unroll
        for (int nt = 0; nt < 2; ++nt)
            bf[nt] = *(const short8v*)&Bs[wc * 32 + nt * 16 + lr][lk * 8];
#pragma unroll
        for (int mt = 0; mt < 2; ++mt)
#pragma unroll
            for (int nt = 0; nt < 2; ++nt)
                acc[mt][nt] = __builtin_amdgcn_mfma_f32_16x16x32_bf16(
                    af[mt], bf[nt], acc[mt][nt], 0, 0, 0);
        __syncthreads();
    }

#pragma unroll
    for (int mt = 0; mt < 2; ++mt)
#pragma unroll
        for (int nt = 0; nt < 2; ++nt) {
            const int col = wc * 32 + nt * 16 + lr;
#pragma unroll
            for (int j = 0; j < 4; ++j) {
                const int row = brow + wr * 32 + mt * 16 + lk * 4 + j;
                float v = acc[mt][nt][j];
                if (cb == 0) {
                    v = phi_fn(v);
                    if (col < 64)
                        Qh[(size_t)row * MM + col] = f2bf(v * 0.125f);
                    else
                        Kh[(size_t)row * MM + (col - 64)] = f2bf(v);
                } else {
                    Vh[(size_t)row * DM + (cb - 1) * 128 + col] = f2bf(v);
                }
            }
        }
}

// ---- intra-chunk attention + summaries, 512 threads, 64-col V slices ----
// grid (NCHUNK, 8, NB) = 512 blocks -> 2 blocks/CU
__global__ __launch_bounds__(512) void chunk_local_mfma(
    const unsigned short* __restrict__ Qb, const unsigned short* __restrict__ Kb,
    const unsigned short* __restrict__ Vb, const float* __restrict__ logit,
    unsigned short* __restrict__ OI, float* __restrict__ DI,
    unsigned short* __restrict__ KV, float* __restrict__ KZ)
{
    const int chunk = blockIdx.x, dg = blockIdx.y, b = blockIdx.z;
    const int tid = threadIdx.x;
    const int lane = tid & 63, w = tid >> 6;    // 8 waves
    const int lr = lane & 15, lk = lane >> 4;
    const int t0 = chunk * CHK;
    const float ld = get_ld(logit);

    __shared__ unsigned short Qs[64][72];
    __shared__ unsigned short Ks[64][72];
    __shared__ unsigned short As[64][72];
    __shared__ unsigned short Kws[64][66];
    __shared__ unsigned short Vs[64][66];   // 64-col slice; stride 33 dw, conflict-free
    __shared__ float wks[64];
    __shared__ float cps[64];
    __shared__ float DIsh[64];

    if (tid < 64) {
        const float c = cpos(ld, t0 + tid);
        cps[tid] = c;
        wks[tid] = expf(cpos(ld, t0 + CHK - 1) - c);
        DIsh[tid] = 0.f;
    }
    __syncthreads();

    // stage Q, K, Kws: 512 groups of 8
    {
        const unsigned short* Qg = Qb + ((size_t)b * LSEQ + t0) * MM;
        const unsigned short* Kg = Kb + ((size_t)b * LSEQ + t0) * MM;
        const int r = tid >> 3, gq = tid & 7;
        *(uint4*)&Qs[r][gq * 8] = *(const uint4*)(Qg + (size_t)tid * 8);
        uint4 kraw = *(const uint4*)(Kg + (size_t)tid * 8);
        *(uint4*)&Ks[r][gq * 8] = kraw;
        const float wv = wks[r];
        const unsigned short* kp = (const unsigned short*)&kraw;
#pragma unroll
        for (int p = 0; p < 4; ++p) {
            ushort2 o;
            o.x = f2bf(wv * bf2f(kp[2 * p]));
            o.y = f2bf(wv * bf2f(kp[2 * p + 1]));
            *(ushort2*)&Kws[r][gq * 8 + 2 * p] = o;
        }
    }
    // stage V slice (64x64): 512 groups of 8
    {
        const unsigned short* Vg = Vb + ((size_t)b * LSEQ + t0) * DM + dg * 64;
        const int s = tid >> 3, gg = tid & 7;
        uint4 vr = *(const uint4*)(Vg + (size_t)s * DM + gg * 8);
        const unsigned short* vp = (const unsigned short*)&vr;
#pragma unroll
        for (int p = 0; p < 4; ++p) {
            ushort2 o;
            o.x = vp[2 * p]; o.y = vp[2 * p + 1];
            *(ushort2*)&Vs[s][gg * 8 + 2 * p] = o;
        }
    }
    __syncthreads();

    // S = Q K^T: 8 waves, each 16 rows x 32 cols
    {
        const int wr2 = w >> 1, wc2 = w & 1;
        f32x4 sacc[2];
        sacc[0] = (f32x4)(0.f); sacc[1] = (f32x4)(0.f);
#pragma unroll
        for (int ks = 0; ks < 2; ++ks) {
            short8v qa = *(const short8v*)&Qs[wr2 * 16 + lr][ks * 32 + lk * 8];
            short8v kb2[2];
#pragma unroll
            for (int nt = 0; nt < 2; ++nt)
                kb2[nt] = *(const short8v*)&Ks[wc2 * 32 + nt * 16 + lr][ks * 32 + lk * 8];
#pragma unroll
            for (int nt = 0; nt < 2; ++nt)
                sacc[nt] = __builtin_amdgcn_mfma_f32_16x16x32_bf16(
                    qa, kb2[nt], sacc[nt], 0, 0, 0);
        }
#pragma unroll
        for (int j = 0; j < 4; ++j) {
            const int t = wr2 * 16 + lk * 4 + j;
            const float ct = cps[t];
            float rowpart = 0.f;
#pragma unroll
            for (int nt = 0; nt < 2; ++nt) {
                const int s = wc2 * 32 + nt * 16 + lr;
                float v = sacc[nt][j];
                v = (s <= t) ? v * expf(ct - cps[s]) : 0.f;
                rowpart += v;
                As[t][s] = f2bf(v);
            }
            rowpart += __shfl_xor(rowpart, 1);
            rowpart += __shfl_xor(rowpart, 2);
            rowpart += __shfl_xor(rowpart, 4);
            rowpart += __shfl_xor(rowpart, 8);
            if (lr == 0) atomicAdd(&DIsh[t], rowpart);
        }
    }
    __syncthreads();

    if (dg == 0) {
        if (tid < 64) DI[(size_t)b * LSEQ + t0 + tid] = DIsh[tid];
        if (tid >= 64 && tid < 128) {
            const int m = tid - 64;
            float z = 0.f;
#pragma unroll
            for (int s = 0; s < 64; ++s) z += wks[s] * bf2f(Ks[s][m]);
            KZ[((size_t)b * NCHUNK + chunk) * MM + m] = z;
        }
    }

    // waves 0-3: O = A.V ; waves 4-7: KV = Kw^T.V  (each 32 rows x 32 cols)
    {
        const int isKV = w >> 2;
        const int w2 = w & 3;
        const int wr = w2 >> 1, wc = w2 & 1;

        f32x4 a2[2][2];
#pragma unroll
        for (int i = 0; i < 2; ++i)
#pragma unroll
            for (int j = 0; j < 2; ++j) a2[i][j] = (f32x4)(0.f);

#pragma unroll
        for (int ks = 0; ks < 2; ++ks) {
            short8v vf[2];
#pragma unroll
            for (int nt = 0; nt < 2; ++nt) {
                unsigned short* vp = (unsigned short*)&vf[nt];
                const int n = wc * 32 + nt * 16 + lr;
#pragma unroll
                for (int e = 0; e < 8; ++e)
                    vp[e] = Vs[ks * 32 + lk * 8 + e][n];
            }
            short8v mf[2];
#pragma unroll
            for (int mt = 0; mt < 2; ++mt) {
                const int row = wr * 32 + mt * 16 + lr;
                if (!isKV) {
                    mf[mt] = *(const short8v*)&As[row][ks * 32 + lk * 8];
                } else {
                    unsigned short* kp = (unsigned short*)&mf[mt];
#pragma unroll
                    for (int e = 0; e < 8; ++e)
                        kp[e] = Kws[ks * 32 + lk * 8 + e][row];
                }
            }
#pragma unroll
            for (int mt = 0; mt < 2; ++mt)
#pragma unroll
                for (int nt = 0; nt < 2; ++nt)
                    a2[mt][nt] = __builtin_amdgcn_mfma_f32_16x16x32_bf16(
                        mf[mt], vf[nt], a2[mt][nt], 0, 0, 0);
        }

        if (!isKV) {
            unsigned short* OIb = OI + ((size_t)b * LSEQ + t0) * DM + dg * 64;
#pragma unroll
            for (int mt = 0; mt < 2; ++mt)
#pragma unroll
                for (int nt = 0; nt < 2; ++nt) {
                    const int col = wc * 32 + nt * 16 + lr;
#pragma unroll
                    for (int j = 0; j < 4; ++j) {
                        const int row = wr * 32 + mt * 16 + lk * 4 + j;
                        OIb[(size_t)row * DM + col] = f2bf(a2[mt][nt][j]);
                    }
                }
        } else {
            unsigned short* KVb = KV + ((size_t)b * NCHUNK + chunk) * MM * DM + dg * 64;
#pragma unroll
            for (int mt = 0; mt < 2; ++mt)
#pragma unroll
                for (int nt = 0; nt < 2; ++nt) {
                    const int col = wc * 32 + nt * 16 + lr;
#pragma unroll
                    for (int j = 0; j < 4; ++j) {
                        const int row = wr * 32 + mt * 16 + lk * 4 + j;
                        KVb[(size_t)row * DM + col] = f2bf(a2[mt][nt][j]);
                    }
                }
        }
    }
}

// ---- sequential scan over chunks (bf16 in/out, fp32 accum). grid 512x128 ----
__global__ __launch_bounds__(128) void state_scan(
    const unsigned short* __restrict__ KV, const float* __restrict__ KZ,
    const float* __restrict__ logit,
    unsigned short* __restrict__ SS, float* __restrict__ ZS)
{
    const int g = blockIdx.x * 128 + threadIdx.x;
    const int b = g >> 15;
    const int rem = g & 32767;
    const int m = rem >> 9;
    const int d = rem & 511;
    const float ld = get_ld(logit);
    const size_t base = (((size_t)b * NCHUNK) * MM + m) * DM + d;
    const size_t cstride = (size_t)MM * DM;

    float v[NCHUNK];
#pragma unroll
    for (int i = 0; i < NCHUNK; ++i) v[i] = bf2f(KV[base + (size_t)i * cstride]);

    float s = 0.f, cprev = 0.f;
#pragma unroll
    for (int i = 0; i < NCHUNK; ++i) {
        const float ce = cpos(ld, i * CHK + CHK - 1);
        const float lam = expf(ce - cprev);
        cprev = ce;
        SS[base + (size_t)i * cstride] = f2bf(s);
        s = lam * s + v[i];
    }
    if (d == 0) {
        float zs = 0.f;
        cprev = 0.f;
#pragma unroll
        for (int i = 0; i < NCHUNK; ++i) {
            const float ce = cpos(ld, i * CHK + CHK - 1);
            const float lam = expf(ce - cprev);
            cprev = ce;
            const int zi = (b * NCHUNK + i) * MM + m;
            ZS[zi] = zs;
            zs = lam * zs + KZ[zi];
        }
    }
}

// ---- fused combine + DEN + RMS -> bf16, 512 threads, quarter-chunks ----
// grid (NCHUNK, 4, NB): 256 blocks, 16 rows each; 8 waves x 64-col slices
__global__ __launch_bounds__(512) void combine_rms(
    const unsigned short* __restrict__ Qb, const unsigned short* __restrict__ SSb,
    const float* __restrict__ ZS, const unsigned short* __restrict__ OI,
    const float* __restrict__ DI, const float* __restrict__ logit,
    const float* __restrict__ norm_w, unsigned short* __restrict__ NRM)
{
    const int chunk = blockIdx.x, quarter = blockIdx.y, b = blockIdx.z;
    const int tid = threadIdx.x;
    const int lane = tid & 63, w = tid >> 6;   // wave -> col block w*64
    const int lr = lane & 15, lk = lane >> 4;
    const int t0 = chunk * CHK;
    const int r0 = quarter * 16;
    const float ld = get_ld(logit);

    __shared__ unsigned short Qs[16][72];
    __shared__ unsigned short Ssh[64][514];   // strided u16 reads conflict-free
    __shared__ float wsh[512];
    __shared__ float gv[16], invden[16], xsq[16], rinv[16];

    // stage Q rows [t0+r0, +16): 128 groups of 8
    if (tid < 128) {
        const unsigned short* Qg = Qb + ((size_t)b * LSEQ + t0 + r0) * MM;
        const int r = tid >> 3, g8 = tid & 7;
        *(uint4*)&Qs[r][g8 * 8] = *(const uint4*)(Qg + (size_t)tid * 8);
    }
    // stage S_prev (64x512 bf16): 4096 groups of 8
    {
        const unsigned short* Sg = SSb + ((size_t)(b * NCHUNK + chunk) * MM) * DM;
#pragma unroll
        for (int l = 0; l < 8; ++l) {
            const int e = tid + l * 512;
            const int m = e >> 6, g8 = e & 63;
            uint4 v = *(const uint4*)(Sg + (size_t)m * DM + g8 * 8);
            const unsigned short* vp = (const unsigned short*)&v;
#pragma unroll
            for (int p = 0; p < 4; ++p) {
                ushort2 o; o.x = vp[2 * p]; o.y = vp[2 * p + 1];
                *(ushort2*)&Ssh[m][g8 * 8 + 2 * p] = o;
            }
        }
    }
    wsh[tid] = norm_w[tid];
    if (tid < 16) {
        const float cprev = (chunk > 0) ? cpos(ld, t0 - 1) : 0.f;
        gv[tid] = expf(cpos(ld, t0 + r0 + tid) - cprev);
        xsq[tid] = 0.f;
    }
    __syncthreads();

    if (tid < 16) {
        const float* zp = ZS + ((size_t)b * NCHUNK + chunk) * MM;
        float a = 0.f;
#pragma unroll
        for (int m = 0; m < MM; ++m) a += bf2f(Qs[tid][m]) * zp[m];
        invden[tid] = 1.0f /
            (gv[tid] * a + DI[(size_t)b * LSEQ + t0 + r0 + tid] + 1e-6f);
    }

    // O_inter = Q(16x64) @ S_prev(64x512): wave w covers cols w*64..+64
    f32x4 acc[4];
#pragma unroll
    for (int j = 0; j < 4; ++j) acc[j] = (f32x4)(0.f);

#pragma unroll
    for (int ks = 0; ks < 2; ++ks) {
        short8v vf[4];
#pragma unroll
        for (int nt = 0; nt < 4; ++nt) {
            unsigned short* vp = (unsigned short*)&vf[nt];
            const int col = w * 64 + nt * 16 + lr;
#pragma unroll
            for (int e = 0; e < 8; ++e)
                vp[e] = Ssh[ks * 32 + lk * 8 + e][col];
        }
        short8v af = *(const short8v*)&Qs[lr][ks * 32 + lk * 8];
#pragma unroll
        for (int nt = 0; nt < 4; ++nt)
            acc[nt] = __builtin_amdgcn_mfma_f32_16x16x32_bf16(
                af, vf[nt], acc[nt], 0, 0, 0);
    }
    __syncthreads();   // invden visible

    const unsigned short* OIb = OI + ((size_t)b * LSEQ + t0 + r0) * DM;
#pragma unroll
    for (int j = 0; j < 4; ++j) {
        const int row = lk * 4 + j;
        const float g = gv[row];
        const float inv = invden[row];
        float part = 0.f;
#pragma unroll
        for (int nt = 0; nt < 4; ++nt) {
            const int col = w * 64 + nt * 16 + lr;
            float v = g * acc[nt][j] + bf2f(OIb[(size_t)row * DM + col]);
            float xx = v * inv;
            acc[nt][j] = xx;
            part += xx * xx;
        }
        part += __shfl_xor(part, 1);
        part += __shfl_xor(part, 2);
        part += __shfl_xor(part, 4);
        part += __shfl_xor(part, 8);
        if (lr == 0) atomicAdd(&xsq[row], part);
    }
    __syncthreads();
    if (tid < 16)
        rinv[tid] = 1.0f / sqrtf(xsq[tid] * (1.0f / (float)DM) + 1e-6f);
    __syncthreads();

    unsigned short* NRMc = NRM + ((size_t)b * LSEQ + t0 + r0) * DM;
#pragma unroll
    for (int j = 0; j < 4; ++j) {
        const int row = lk * 4 + j;
        const float r = rinv[row];
#pragma unroll
        for (int nt = 0; nt < 4; ++nt) {
            const int col = w * 64 + nt * 16 + lr;
            NRMc[(size_t)row * DM + col] = f2bf(acc[nt][j] * r * wsh[col]);
        }
    }
}

// ---- output GEMM: 64x64 tiles, 512 threads, grid (64,8) = 512 blocks ----
__global__ __launch_bounds__(512) void gemm_out(
    const unsigned short* __restrict__ Xb, const unsigned short* __restrict__ Wb,
    float* __restrict__ C)
{
    __shared__ unsigned short As[64][40];
    __shared__ unsigned short Bs[64][40];
    const int brow = blockIdx.x * 64;
    const int bcol = blockIdx.y * 64;
    const int tid = threadIdx.x;
    const int lane = tid & 63, w = tid >> 6;    // 8 waves
    const int wrow = w & 3, wcol = w >> 2;      // 16-row grp, 32-col grp
    const int lr = lane & 15, lk = lane >> 4;

    f32x4 acc[2];
    acc[0] = (f32x4)(0.f); acc[1] = (f32x4)(0.f);

    for (int k0 = 0; k0 < DM; k0 += 32) {
        {
            const int r = (tid & 255) >> 2, kg = tid & 3;
            if (tid < 256)
                *(uint4*)&As[r][kg * 8] =
                    *(const uint4*)&Xb[(size_t)(brow + r) * DM + k0 + kg * 8];
            else
                *(uint4*)&Bs[r][kg * 8] =
                    *(const uint4*)&Wb[(size_t)(bcol + r) * DM + k0 + kg * 8];
        }
        __syncthreads();
        short8v af = *(const short8v*)&As[wrow * 16 + lr][lk * 8];
        short8v bf[2];
#pragma unroll
        for (int nt = 0; nt < 2; ++nt)
            bf[nt] = *(const short8v*)&Bs[wcol * 32 + nt * 16 + lr][lk * 8];
#pragma unroll
        for (int nt = 0; nt < 2; ++nt)
            acc[nt] = __builtin_amdgcn_mfma_f32_16x16x32_bf16(
                af, bf[nt], acc[nt], 0, 0, 0);
        __syncthreads();
    }

#pragma unroll
    for (int nt = 0; nt < 2; ++nt) {
        const int row0 = brow + wrow * 16 + lk * 4;
        const int col = bcol + wcol * 32 + nt * 16 + lr;
#pragma unroll
        for (int j = 0; j < 4; ++j)
            C[(size_t)(row0 + j) * DM + col] = acc[nt][j];
    }
}

extern "C" void kernel_launch(void* const* d_in, const int* in_sizes, int n_in,
                              void* d_out, int out_size, void* d_ws, size_t ws_size,
                              hipStream_t stream) {
    const float* x      = (const float*)d_in[0];
    const float* W_q    = (const float*)d_in[1];
    const float* W_k    = (const float*)d_in[2];
    const float* W_v    = (const float*)d_in[3];
    const float* W_o    = (const float*)d_in[4];
    const float* logit  = (const float*)d_in[5];
    const float* norm_w = (const float*)d_in[6];
    float* out = (float*)d_out;

    const size_t BLM = (size_t)NB * LSEQ * MM;          // 262144
    const size_t BLD = (size_t)NB * LSEQ * DM;          // 2097152
    const size_t BL  = (size_t)NB * LSEQ;               // 4096
    const size_t BNCMD = (size_t)NB * NCHUNK * MM * DM; // 2097152
    const size_t BNCM  = (size_t)NB * NCHUNK * MM;      // 4096
    const size_t WSZ = (size_t)DM * DM;                 // 262144

    float* ws = (float*)d_ws;
    float* DIp = ws;                       // BL
    float* KZp = DIp + BL;                 // BNCM
    float* ZSp = KZp + BNCM;               // BNCM
    unsigned short* OIb  = (unsigned short*)(ZSp + BNCM);  // BLD
    unsigned short* KVb  = OIb + BLD;      // BNCMD
    unsigned short* SSb  = KVb + BNCMD;    // BNCMD
    unsigned short* Wob16 = SSb + BNCMD;   // WSZ
    unsigned short* Qb16 = Wob16 + WSZ;    // BLM
    unsigned short* Kb16 = Qb16 + BLM;     // BLM
    unsigned short* Vb16 = Kb16 + BLM;     // BLD
    unsigned short* NRMb = Vb16 + BLD;     // BLD

    // 1. fused QKV projection (+ W_o cvt)
    gemm_proj<<<dim3(64, 6), 512, 0, stream>>>(x, W_q, W_k, W_v, W_o,
                                               Qb16, Kb16, Vb16, Wob16);
    // 2. intra-chunk attention + summaries (512 blocks, 2/CU)
    chunk_local_mfma<<<dim3(NCHUNK, 8, NB), 512, 0, stream>>>(
        Qb16, Kb16, Vb16, logit, OIb, DIp, KVb, KZp);
    // 3. sequential state scan (bf16 in/out)
    state_scan<<<dim3(512), 128, 0, stream>>>(KVb, KZp, logit, SSb, ZSp);
    // 4. combine + DEN + RMS -> bf16 (quarter-chunks, 256 blocks, 8 waves)
    combine_rms<<<dim3(NCHUNK, 4, NB), 512, 0, stream>>>(
        Qb16, SSb, ZSp, OIb, DIp, logit, norm_w, NRMb);
    // 5. output projection (512 blocks, 2/CU)
    gemm_out<<<dim3(64, 8), 512, 0, stream>>>(NRMb, Wob16, out);
}

// Round 13
// 55.189 us; speedup vs baseline: 1.1205x; 1.0044x over previous
//
#include <hip/hip_runtime.h>
#include <math.h>

#define NB 2
#define LSEQ 2048
#define DM 512
#define MM 64
#define CHK 64
#define NCHUNK 32

typedef __attribute__((ext_vector_type(8))) short short8v;
typedef __attribute__((ext_vector_type(4))) float f32x4;

__device__ __forceinline__ float get_ld(const float* __restrict__ logit) {
    float lg = *logit;
    float dec = 1.0f / (1.0f + expf(-lg));
    dec = fmaxf(dec, 1e-6f);
    return logf(dec);
}
__device__ __forceinline__ float cpos(float ld, int t) {
    return fminf(fmaxf(ld * (float)t, -20.0f), 20.0f);
}
__device__ __forceinline__ float phi_fn(float v) {
    return v > 0.0f ? v + 1.0f : expf(v);
}
__device__ __forceinline__ unsigned short f2bf(float f) {
    unsigned int u = __float_as_uint(f);
    u += 0x7FFFu + ((u >> 16) & 1u);   // RNE
    return (unsigned short)(u >> 16);
}
__device__ __forceinline__ float bf2f(unsigned short h) {
    unsigned int u = ((unsigned int)h) << 16;
    return __uint_as_float(u);
}
// load 8 f32, convert to 8 bf16 packed in a uint4
__device__ __forceinline__ uint4 cvt8(const float* __restrict__ p) {
    float4 a = *(const float4*)p;
    float4 b = *(const float4*)(p + 4);
    union { unsigned short u[8]; uint4 v; } r;
    r.u[0] = f2bf(a.x); r.u[1] = f2bf(a.y); r.u[2] = f2bf(a.z); r.u[3] = f2bf(a.w);
    r.u[4] = f2bf(b.x); r.u[5] = f2bf(b.y); r.u[6] = f2bf(b.z); r.u[7] = f2bf(b.w);
    return r.v;
}

// ---- fused QKV projection (cvt-on-the-fly) + W_o cvt slice, 512 threads ----
// grid (64, 6): y=0 QK (cols = Wq|Wk), y=1..4 V col slices, y=5 W_o cvt
__global__ __launch_bounds__(512) void gemm_proj(
    const float* __restrict__ x, const float* __restrict__ W_q,
    const float* __restrict__ W_k, const float* __restrict__ W_v,
    const float* __restrict__ W_o,
    unsigned short* __restrict__ Qh, unsigned short* __restrict__ Kh,
    unsigned short* __restrict__ Vh, unsigned short* __restrict__ Wob)
{
    const int cb = blockIdx.y;
    const int tid = threadIdx.x;
    if (cb == 5) {  // W_o -> bf16 (64 blocks x 512 thr x 2 float4)
        const int stride = 64 * 512;
#pragma unroll
        for (int it = 0; it < 2; ++it) {
            int i = blockIdx.x * 512 + tid + it * stride;
            float4 v = ((const float4*)W_o)[i];
            ushort4 o;
            o.x = f2bf(v.x); o.y = f2bf(v.y); o.z = f2bf(v.z); o.w = f2bf(v.w);
            ((ushort4*)Wob)[i] = o;
        }
        return;
    }

    __shared__ unsigned short As[64][40];
    __shared__ unsigned short Bs[128][40];
    const int brow = blockIdx.x * 64;
    const int lane = tid & 63, w = tid >> 6;     // 8 waves
    const int wr = w >> 2, wc = w & 3;           // 2x4: rows wr*32, cols wc*32
    const int lr = lane & 15, lk = lane >> 4;

    f32x4 acc[2][2];
#pragma unroll
    for (int i = 0; i < 2; ++i)
#pragma unroll
        for (int j = 0; j < 2; ++j) acc[i][j] = (f32x4)(0.f);

    for (int k0 = 0; k0 < DM; k0 += 32) {
        if (tid < 256) {   // A tile: 64x32 = 256 groups of 8
            const int r = tid >> 2, kg = tid & 3;
            *(uint4*)&As[r][kg * 8] = cvt8(&x[(size_t)(brow + r) * DM + k0 + kg * 8]);
        }
        {   // B tile: 128x32 = 512 groups
            const int r = tid >> 2, kg = tid & 3;
            const float* wsrc;
            if (cb == 0)
                wsrc = (r < 64) ? &W_q[(size_t)r * DM + k0 + kg * 8]
                                : &W_k[(size_t)(r - 64) * DM + k0 + kg * 8];
            else
                wsrc = &W_v[(size_t)((cb - 1) * 128 + r) * DM + k0 + kg * 8];
            *(uint4*)&Bs[r][kg * 8] = cvt8(wsrc);
        }
        __syncthreads();
        short8v af[2], bf[2];
#pragma unroll
        for (int mt = 0; mt < 2; ++mt)
            af[mt] = *(const short8v*)&As[wr * 32 + mt * 16 + lr][lk * 8];
#pragma unroll
        for (int nt = 0; nt < 2; ++nt)
            bf[nt] = *(const short8v*)&Bs[wc * 32 + nt * 16 + lr][lk * 8];
#pragma unroll
        for (int mt = 0; mt < 2; ++mt)
#pragma unroll
            for (int nt = 0; nt < 2; ++nt)
                acc[mt][nt] = __builtin_amdgcn_mfma_f32_16x16x32_bf16(
                    af[mt], bf[nt], acc[mt][nt], 0, 0, 0);
        __syncthreads();
    }

#pragma unroll
    for (int mt = 0; mt < 2; ++mt)
#pragma unroll
        for (int nt = 0; nt < 2; ++nt) {
            const int col = wc * 32 + nt * 16 + lr;
#pragma unroll
            for (int j = 0; j < 4; ++j) {
                const int row = brow + wr * 32 + mt * 16 + lk * 4 + j;
                float v = acc[mt][nt][j];
                if (cb == 0) {
                    v = phi_fn(v);
                    if (col < 64)
                        Qh[(size_t)row * MM + col] = f2bf(v * 0.125f);
                    else
                        Kh[(size_t)row * MM + (col - 64)] = f2bf(v);
                } else {
                    Vh[(size_t)row * DM + (cb - 1) * 128 + col] = f2bf(v);
                }
            }
        }
}

// ---- intra-chunk attention + summaries, 512 threads, 64-col V slices ----
// grid (NCHUNK, 8, NB) = 512 blocks -> 2 blocks/CU
__global__ __launch_bounds__(512) void chunk_local_mfma(
    const unsigned short* __restrict__ Qb, const unsigned short* __restrict__ Kb,
    const unsigned short* __restrict__ Vb, const float* __restrict__ logit,
    unsigned short* __restrict__ OI, float* __restrict__ DI,
    unsigned short* __restrict__ KV, float* __restrict__ KZ)
{
    const int chunk = blockIdx.x, dg = blockIdx.y, b = blockIdx.z;
    const int tid = threadIdx.x;
    const int lane = tid & 63, w = tid >> 6;    // 8 waves
    const int lr = lane & 15, lk = lane >> 4;
    const int t0 = chunk * CHK;
    const float ld = get_ld(logit);

    __shared__ unsigned short Qs[64][72];
    __shared__ unsigned short Ks[64][72];
    __shared__ unsigned short As[64][72];
    __shared__ unsigned short Kws[64][66];
    __shared__ unsigned short Vs[64][66];   // 64-col slice; stride 33 dw, conflict-free
    __shared__ float wks[64];
    __shared__ float cps[64];
    __shared__ float DIsh[64];

    if (tid < 64) {
        const float c = cpos(ld, t0 + tid);
        cps[tid] = c;
        wks[tid] = expf(cpos(ld, t0 + CHK - 1) - c);
        DIsh[tid] = 0.f;
    }
    __syncthreads();

    // stage Q, K, Kws: 512 groups of 8
    {
        const unsigned short* Qg = Qb + ((size_t)b * LSEQ + t0) * MM;
        const unsigned short* Kg = Kb + ((size_t)b * LSEQ + t0) * MM;
        const int r = tid >> 3, gq = tid & 7;
        *(uint4*)&Qs[r][gq * 8] = *(const uint4*)(Qg + (size_t)tid * 8);
        uint4 kraw = *(const uint4*)(Kg + (size_t)tid * 8);
        *(uint4*)&Ks[r][gq * 8] = kraw;
        const float wv = wks[r];
        const unsigned short* kp = (const unsigned short*)&kraw;
#pragma unroll
        for (int p = 0; p < 4; ++p) {
            ushort2 o;
            o.x = f2bf(wv * bf2f(kp[2 * p]));
            o.y = f2bf(wv * bf2f(kp[2 * p + 1]));
            *(ushort2*)&Kws[r][gq * 8 + 2 * p] = o;
        }
    }
    // stage V slice (64x64): 512 groups of 8
    {
        const unsigned short* Vg = Vb + ((size_t)b * LSEQ + t0) * DM + dg * 64;
        const int s = tid >> 3, gg = tid & 7;
        uint4 vr = *(const uint4*)(Vg + (size_t)s * DM + gg * 8);
        const unsigned short* vp = (const unsigned short*)&vr;
#pragma unroll
        for (int p = 0; p < 4; ++p) {
            ushort2 o;
            o.x = vp[2 * p]; o.y = vp[2 * p + 1];
            *(ushort2*)&Vs[s][gg * 8 + 2 * p] = o;
        }
    }
    __syncthreads();

    // S = Q K^T: 8 waves, each 16 rows x 32 cols
    {
        const int wr2 = w >> 1, wc2 = w & 1;
        f32x4 sacc[2];
        sacc[0] = (f32x4)(0.f); sacc[1] = (f32x4)(0.f);
#pragma unroll
        for (int ks = 0; ks < 2; ++ks) {
            short8v qa = *(const short8v*)&Qs[wr2 * 16 + lr][ks * 32 + lk * 8];
            short8v kb2[2];
#pragma unroll
            for (int nt = 0; nt < 2; ++nt)
                kb2[nt] = *(const short8v*)&Ks[wc2 * 32 + nt * 16 + lr][ks * 32 + lk * 8];
#pragma unroll
            for (int nt = 0; nt < 2; ++nt)
                sacc[nt] = __builtin_amdgcn_mfma_f32_16x16x32_bf16(
                    qa, kb2[nt], sacc[nt], 0, 0, 0);
        }
#pragma unroll
        for (int j = 0; j < 4; ++j) {
            const int t = wr2 * 16 + lk * 4 + j;
            const float ct = cps[t];
            float rowpart = 0.f;
#pragma unroll
            for (int nt = 0; nt < 2; ++nt) {
                const int s = wc2 * 32 + nt * 16 + lr;
                float v = sacc[nt][j];
                v = (s <= t) ? v * expf(ct - cps[s]) : 0.f;
                rowpart += v;
                As[t][s] = f2bf(v);
            }
            rowpart += __shfl_xor(rowpart, 1);
            rowpart += __shfl_xor(rowpart, 2);
            rowpart += __shfl_xor(rowpart, 4);
            rowpart += __shfl_xor(rowpart, 8);
            if (lr == 0) atomicAdd(&DIsh[t], rowpart);
        }
    }
    __syncthreads();

    if (dg == 0) {
        if (tid < 64) DI[(size_t)b * LSEQ + t0 + tid] = DIsh[tid];
        if (tid >= 64 && tid < 128) {
            const int m = tid - 64;
            float z = 0.f;
#pragma unroll
            for (int s = 0; s < 64; ++s) z += wks[s] * bf2f(Ks[s][m]);
            KZ[((size_t)b * NCHUNK + chunk) * MM + m] = z;
        }
    }

    // waves 0-3: O = A.V ; waves 4-7: KV = Kw^T.V  (each 32 rows x 32 cols)
    {
        const int isKV = w >> 2;
        const int w2 = w & 3;
        const int wr = w2 >> 1, wc = w2 & 1;

        f32x4 a2[2][2];
#pragma unroll
        for (int i = 0; i < 2; ++i)
#pragma unroll
            for (int j = 0; j < 2; ++j) a2[i][j] = (f32x4)(0.f);

#pragma unroll
        for (int ks = 0; ks < 2; ++ks) {
            short8v vf[2];
#pragma unroll
            for (int nt = 0; nt < 2; ++nt) {
                unsigned short* vp = (unsigned short*)&vf[nt];
                const int n = wc * 32 + nt * 16 + lr;
#pragma unroll
                for (int e = 0; e < 8; ++e)
                    vp[e] = Vs[ks * 32 + lk * 8 + e][n];
            }
            short8v mf[2];
#pragma unroll
            for (int mt = 0; mt < 2; ++mt) {
                const int row = wr * 32 + mt * 16 + lr;
                if (!isKV) {
                    mf[mt] = *(const short8v*)&As[row][ks * 32 + lk * 8];
                } else {
                    unsigned short* kp = (unsigned short*)&mf[mt];
#pragma unroll
                    for (int e = 0; e < 8; ++e)
                        kp[e] = Kws[ks * 32 + lk * 8 + e][row];
                }
            }
#pragma unroll
            for (int mt = 0; mt < 2; ++mt)
#pragma unroll
                for (int nt = 0; nt < 2; ++nt)
                    a2[mt][nt] = __builtin_amdgcn_mfma_f32_16x16x32_bf16(
                        mf[mt], vf[nt], a2[mt][nt], 0, 0, 0);
        }

        if (!isKV) {
            unsigned short* OIb = OI + ((size_t)b * LSEQ + t0) * DM + dg * 64;
#pragma unroll
            for (int mt = 0; mt < 2; ++mt)
#pragma unroll
                for (int nt = 0; nt < 2; ++nt) {
                    const int col = wc * 32 + nt * 16 + lr;
#pragma unroll
                    for (int j = 0; j < 4; ++j) {
                        const int row = wr * 32 + mt * 16 + lk * 4 + j;
                        OIb[(size_t)row * DM + col] = f2bf(a2[mt][nt][j]);
                    }
                }
        } else {
            unsigned short* KVb = KV + ((size_t)b * NCHUNK + chunk) * MM * DM + dg * 64;
#pragma unroll
            for (int mt = 0; mt < 2; ++mt)
#pragma unroll
                for (int nt = 0; nt < 2; ++nt) {
                    const int col = wc * 32 + nt * 16 + lr;
#pragma unroll
                    for (int j = 0; j < 4; ++j) {
                        const int row = wr * 32 + mt * 16 + lk * 4 + j;
                        KVb[(size_t)row * DM + col] = f2bf(a2[mt][nt][j]);
                    }
                }
        }
    }
}

// ---- sequential scan over chunks (bf16 in/out, fp32 accum). grid 512x128 ----
__global__ __launch_bounds__(128) void state_scan(
    const unsigned short* __restrict__ KV, const float* __restrict__ KZ,
    const float* __restrict__ logit,
    unsigned short* __restrict__ SS, float* __restrict__ ZS)
{
    const int g = blockIdx.x * 128 + threadIdx.x;
    const int b = g >> 15;
    const int rem = g & 32767;
    const int m = rem >> 9;
    const int d = rem & 511;
    const float ld = get_ld(logit);
    const size_t base = (((size_t)b * NCHUNK) * MM + m) * DM + d;
    const size_t cstride = (size_t)MM * DM;

    float v[NCHUNK];
#pragma unroll
    for (int i = 0; i < NCHUNK; ++i) v[i] = bf2f(KV[base + (size_t)i * cstride]);

    float s = 0.f, cprev = 0.f;
#pragma unroll
    for (int i = 0; i < NCHUNK; ++i) {
        const float ce = cpos(ld, i * CHK + CHK - 1);
        const float lam = expf(ce - cprev);
        cprev = ce;
        SS[base + (size_t)i * cstride] = f2bf(s);
        s = lam * s + v[i];
    }
    if (d == 0) {
        float zs = 0.f;
        cprev = 0.f;
#pragma unroll
        for (int i = 0; i < NCHUNK; ++i) {
            const float ce = cpos(ld, i * CHK + CHK - 1);
            const float lam = expf(ce - cprev);
            cprev = ce;
            const int zi = (b * NCHUNK + i) * MM + m;
            ZS[zi] = zs;
            zs = lam * zs + KZ[zi];
        }
    }
}

// ---- fused combine + DEN + RMS -> bf16, 512 threads, quarter-chunks ----
// grid (NCHUNK, 4, NB): 256 blocks, 16 rows each; 8 waves x 64-col slices
__global__ __launch_bounds__(512) void combine_rms(
    const unsigned short* __restrict__ Qb, const unsigned short* __restrict__ SSb,
    const float* __restrict__ ZS, const unsigned short* __restrict__ OI,
    const float* __restrict__ DI, const float* __restrict__ logit,
    const float* __restrict__ norm_w, unsigned short* __restrict__ NRM)
{
    const int chunk = blockIdx.x, quarter = blockIdx.y, b = blockIdx.z;
    const int tid = threadIdx.x;
    const int lane = tid & 63, w = tid >> 6;   // wave -> col block w*64
    const int lr = lane & 15, lk = lane >> 4;
    const int t0 = chunk * CHK;
    const int r0 = quarter * 16;
    const float ld = get_ld(logit);

    __shared__ unsigned short Qs[16][72];
    __shared__ unsigned short Ssh[64][514];   // strided u16 reads conflict-free
    __shared__ float wsh[512];
    __shared__ float gv[16], invden[16], xsq[16], rinv[16];

    // stage Q rows [t0+r0, +16): 128 groups of 8
    if (tid < 128) {
        const unsigned short* Qg = Qb + ((size_t)b * LSEQ + t0 + r0) * MM;
        const int r = tid >> 3, g8 = tid & 7;
        *(uint4*)&Qs[r][g8 * 8] = *(const uint4*)(Qg + (size_t)tid * 8);
    }
    // stage S_prev (64x512 bf16): 4096 groups of 8
    {
        const unsigned short* Sg = SSb + ((size_t)(b * NCHUNK + chunk) * MM) * DM;
#pragma unroll
        for (int l = 0; l < 8; ++l) {
            const int e = tid + l * 512;
            const int m = e >> 6, g8 = e & 63;
            uint4 v = *(const uint4*)(Sg + (size_t)m * DM + g8 * 8);
            const unsigned short* vp = (const unsigned short*)&v;
#pragma unroll
            for (int p = 0; p < 4; ++p) {
                ushort2 o; o.x = vp[2 * p]; o.y = vp[2 * p + 1];
                *(ushort2*)&Ssh[m][g8 * 8 + 2 * p] = o;
            }
        }
    }
    wsh[tid] = norm_w[tid];
    if (tid < 16) {
        const float cprev = (chunk > 0) ? cpos(ld, t0 - 1) : 0.f;
        gv[tid] = expf(cpos(ld, t0 + r0 + tid) - cprev);
        xsq[tid] = 0.f;
    }
    __syncthreads();

    if (tid < 16) {
        const float* zp = ZS + ((size_t)b * NCHUNK + chunk) * MM;
        float a = 0.f;
#pragma unroll
        for (int m = 0; m < MM; ++m) a += bf2f(Qs[tid][m]) * zp[m];
        invden[tid] = 1.0f /
            (gv[tid] * a + DI[(size_t)b * LSEQ + t0 + r0 + tid] + 1e-6f);
    }

    // O_inter = Q(16x64) @ S_prev(64x512): wave w covers cols w*64..+64
    f32x4 acc[4];
#pragma unroll
    for (int j = 0; j < 4; ++j) acc[j] = (f32x4)(0.f);

#pragma unroll
    for (int ks = 0; ks < 2; ++ks) {
        short8v vf[4];
#pragma unroll
        for (int nt = 0; nt < 4; ++nt) {
            unsigned short* vp = (unsigned short*)&vf[nt];
            const int col = w * 64 + nt * 16 + lr;
#pragma unroll
            for (int e = 0; e < 8; ++e)
                vp[e] = Ssh[ks * 32 + lk * 8 + e][col];
        }
        short8v af = *(const short8v*)&Qs[lr][ks * 32 + lk * 8];
#pragma unroll
        for (int nt = 0; nt < 4; ++nt)
            acc[nt] = __builtin_amdgcn_mfma_f32_16x16x32_bf16(
                af, vf[nt], acc[nt], 0, 0, 0);
    }
    __syncthreads();   // invden visible

    const unsigned short* OIb = OI + ((size_t)b * LSEQ + t0 + r0) * DM;
#pragma unroll
    for (int j = 0; j < 4; ++j) {
        const int row = lk * 4 + j;
        const float g = gv[row];
        const float inv = invden[row];
        float part = 0.f;
#pragma unroll
        for (int nt = 0; nt < 4; ++nt) {
            const int col = w * 64 + nt * 16 + lr;
            float v = g * acc[nt][j] + bf2f(OIb[(size_t)row * DM + col]);
            float xx = v * inv;
            acc[nt][j] = xx;
            part += xx * xx;
        }
        part += __shfl_xor(part, 1);
        part += __shfl_xor(part, 2);
        part += __shfl_xor(part, 4);
        part += __shfl_xor(part, 8);
        if (lr == 0) atomicAdd(&xsq[row], part);
    }
    __syncthreads();
    if (tid < 16)
        rinv[tid] = 1.0f / sqrtf(xsq[tid] * (1.0f / (float)DM) + 1e-6f);
    __syncthreads();

    unsigned short* NRMc = NRM + ((size_t)b * LSEQ + t0 + r0) * DM;
#pragma unroll
    for (int j = 0; j < 4; ++j) {
        const int row = lk * 4 + j;
        const float r = rinv[row];
#pragma unroll
        for (int nt = 0; nt < 4; ++nt) {
            const int col = w * 64 + nt * 16 + lr;
            NRMc[(size_t)row * DM + col] = f2bf(acc[nt][j] * r * wsh[col]);
        }
    }
}

// ---- output GEMM: 64x64 tiles, 512 threads, grid (64,8) = 512 blocks ----
__global__ __launch_bounds__(512) void gemm_out(
    const unsigned short* __restrict__ Xb, const unsigned short* __restrict__ Wb,
    float* __restrict__ C)
{
    __shared__ unsigned short As[64][40];
    __shared__ unsigned short Bs[64][40];
    const int brow = blockIdx.x * 64;
    const int bcol = blockIdx.y * 64;
    const int tid = threadIdx.x;
    const int lane = tid & 63, w = tid >> 6;    // 8 waves
    const int wrow = w & 3, wcol = w >> 2;      // 16-row grp, 32-col grp
    const int lr = lane & 15, lk = lane >> 4;

    f32x4 acc[2];
    acc[0] = (f32x4)(0.f); acc[1] = (f32x4)(0.f);

    for (int k0 = 0; k0 < DM; k0 += 32) {
        {
            const int r = (tid & 255) >> 2, kg = tid & 3;
            if (tid < 256)
                *(uint4*)&As[r][kg * 8] =
                    *(const uint4*)&Xb[(size_t)(brow + r) * DM + k0 + kg * 8];
            else
                *(uint4*)&Bs[r][kg * 8] =
                    *(const uint4*)&Wb[(size_t)(bcol + r) * DM + k0 + kg * 8];
        }
        __syncthreads();
        short8v af = *(const short8v*)&As[wrow * 16 + lr][lk * 8];
        short8v bf[2];
#pragma unroll
        for (int nt = 0; nt < 2; ++nt)
            bf[nt] = *(const short8v*)&Bs[wcol * 32 + nt * 16 + lr][lk * 8];
#pragma unroll
        for (int nt = 0; nt < 2; ++nt)
            acc[nt] = __builtin_amdgcn_mfma_f32_16x16x32_bf16(
                af, bf[nt], acc[nt], 0, 0, 0);
        __syncthreads();
    }

#pragma unroll
    for (int nt = 0; nt < 2; ++nt) {
        const int row0 = brow + wrow * 16 + lk * 4;
        const int col = bcol + wcol * 32 + nt * 16 + lr;
#pragma unroll
        for (int j = 0; j < 4; ++j)
            C[(size_t)(row0 + j) * DM + col] = acc[nt][j];
    }
}

extern "C" void kernel_launch(void* const* d_in, const int* in_sizes, int n_in,
                              void* d_out, int out_size, void* d_ws, size_t ws_size,
                              hipStream_t stream) {
    const float* x      = (const float*)d_in[0];
    const float* W_q    = (const float*)d_in[1];
    const float* W_k    = (const float*)d_in[2];
    const float* W_v    = (const float*)d_in[3];
    const float* W_o    = (const float*)d_in[4];
    const float* logit  = (const float*)d_in[5];
    const float* norm_w = (const float*)d_in[6];
    float* out = (float*)d_out;

    const size_t BLM = (size_t)NB * LSEQ * MM;          // 262144
    const size_t BLD = (size_t)NB * LSEQ * DM;          // 2097152
    const size_t BL  = (size_t)NB * LSEQ;               // 4096
    const size_t BNCMD = (size_t)NB * NCHUNK * MM * DM; // 2097152
    const size_t BNCM  = (size_t)NB * NCHUNK * MM;      // 4096
    const size_t WSZ = (size_t)DM * DM;                 // 262144

    float* ws = (float*)d_ws;
    float* DIp = ws;                       // BL
    float* KZp = DIp + BL;                 // BNCM
    float* ZSp = KZp + BNCM;               // BNCM
    unsigned short* OIb  = (unsigned short*)(ZSp + BNCM);  // BLD
    unsigned short* KVb  = OIb + BLD;      // BNCMD
    unsigned short* SSb  = KVb + BNCMD;    // BNCMD
    unsigned short* Wob16 = SSb + BNCMD;   // WSZ
    unsigned short* Qb16 = Wob16 + WSZ;    // BLM
    unsigned short* Kb16 = Qb16 + BLM;     // BLM
    unsigned short* Vb16 = Kb16 + BLM;     // BLD
    unsigned short* NRMb = Vb16 + BLD;     // BLD

    // 1. fused QKV projection (+ W_o cvt)
    gemm_proj<<<dim3(64, 6), 512, 0, stream>>>(x, W_q, W_k, W_v, W_o,
                                               Qb16, Kb16, Vb16, Wob16);
    // 2. intra-chunk attention + summaries (512 blocks, 2/CU)
    chunk_local_mfma<<<dim3(NCHUNK, 8, NB), 512, 0, stream>>>(
        Qb16, Kb16, Vb16, logit, OIb, DIp, KVb, KZp);
    // 3. sequential state scan (bf16 in/out)
    state_scan<<<dim3(512), 128, 0, stream>>>(KVb, KZp, logit, SSb, ZSp);
    // 4. combine + DEN + RMS -> bf16 (quarter-chunks, 256 blocks, 8 waves)
    combine_rms<<<dim3(NCHUNK, 4, NB), 512, 0, stream>>>(
        Qb16, SSb, ZSp, OIb, DIp, logit, norm_w, NRMb);
    // 5. output projection (512 blocks, 2/CU)
    gemm_out<<<dim3(64, 8), 512, 0, stream>>>(NRMb, Wob16, out);
}